// Round 1
// baseline (1235.822 us; speedup 1.0000x reference)
//
#include <hip/hip_runtime.h>
#include <hip/hip_bf16.h>
#include <cstdint>
#include <cstddef>

namespace {

constexpr int S_LEN = 2048;
constexpr int DM    = 4096;
constexpr int NH    = 32;
constexpr int NKV   = 8;
constexpr int DH    = 128;
constexpr int LTAB  = 20;
constexpr int RBKT  = 128;

typedef short s16x8 __attribute__((ext_vector_type(8)));
typedef float f32x4 __attribute__((ext_vector_type(4)));

// ---------------- fp32 -> bf16 (flat) ----------------
__global__ __launch_bounds__(256) void cvt_f32_bf16(const float* __restrict__ in,
                                                    __hip_bfloat16* __restrict__ out,
                                                    int n4) {
  int i = blockIdx.x * blockDim.x + threadIdx.x;
  if (i >= n4) return;
  float4 v = reinterpret_cast<const float4*>(in)[i];
  __hip_bfloat16 a = __float2bfloat16(v.x);
  __hip_bfloat16 b = __float2bfloat16(v.y);
  __hip_bfloat16 c = __float2bfloat16(v.z);
  __hip_bfloat16 d = __float2bfloat16(v.w);
  ushort4 o;
  o.x = *reinterpret_cast<unsigned short*>(&a);
  o.y = *reinterpret_cast<unsigned short*>(&b);
  o.z = *reinterpret_cast<unsigned short*>(&c);
  o.w = *reinterpret_cast<unsigned short*>(&d);
  reinterpret_cast<ushort4*>(out)[i] = o;
}

// ---------------- transpose + convert: W[K][N] f32 -> Wt[N][K] bf16 ----------------
__global__ __launch_bounds__(256) void transpose_cvt(const float* __restrict__ W,
                                                     __hip_bfloat16* __restrict__ Wt,
                                                     int K, int N) {
  __shared__ float tile[32][33];
  const int kb = blockIdx.y * 32, nb = blockIdx.x * 32;
  const int tx = threadIdx.x, ty = threadIdx.y;
#pragma unroll
  for (int i = ty; i < 32; i += 8)
    tile[i][tx] = W[(size_t)(kb + i) * N + nb + tx];
  __syncthreads();
#pragma unroll
  for (int i = ty; i < 32; i += 8)
    Wt[(size_t)(nb + i) * K + kb + tx] = __float2bfloat16(tile[tx][i]);
}

// ---------------- bf16 GEMM: C[M][N] = A[M][K] * Bt[N][K]^T ----------------
// 128x128 tile, BK=64, 4 waves (2x2), mfma 16x16x32, swizzled global_load_lds staging.
template <bool OUT_F32>
__global__ __launch_bounds__(256) void gemm_bt(const __hip_bfloat16* __restrict__ A,
                                               const __hip_bfloat16* __restrict__ Bt,
                                               void* __restrict__ Cout,
                                               int N, int K) {
  __shared__ __hip_bfloat16 As[128 * 64];
  __shared__ __hip_bfloat16 Bs[128 * 64];
  const int tid = threadIdx.x;
  const int wid = tid >> 6;
  const int lane = tid & 63;
  const int bm = blockIdx.y, bn = blockIdx.x;
  const int wr = wid >> 1, wc = wid & 1;
  f32x4 acc[4][4] = {};
  const __hip_bfloat16* Abase = A + (size_t)bm * 128 * K;
  const __hip_bfloat16* Bbase = Bt + (size_t)bn * 128 * K;
  for (int kt = 0; kt < K; kt += 64) {
    __syncthreads();
#pragma unroll
    for (int j = 0; j < 4; ++j) {
      const int pb = j * 4096 + wid * 1024;  // wave-uniform LDS byte base
      const int p = pb + lane * 16;          // this lane's linear dest byte
      const int row = p >> 7;                // 0..127 (row = 128B of bf16, BK=64)
      const int slot = ((p >> 4) & 7) ^ (row & 7);  // inverse-swizzled source slot
      const int goff = row * K + kt + slot * 8;
      __builtin_amdgcn_global_load_lds(
          (const __attribute__((address_space(1))) void*)(Abase + goff),
          (__attribute__((address_space(3))) void*)(As + (pb >> 1)), 16, 0, 0);
      __builtin_amdgcn_global_load_lds(
          (const __attribute__((address_space(1))) void*)(Bbase + goff),
          (__attribute__((address_space(3))) void*)(Bs + (pb >> 1)), 16, 0, 0);
    }
    __syncthreads();
#pragma unroll
    for (int kk = 0; kk < 2; ++kk) {
      s16x8 af[4], bf[4];
#pragma unroll
      for (int i = 0; i < 4; ++i) {
        const int ra = wr * 64 + i * 16 + (lane & 15);
        const int sa = (kk * 4 + (lane >> 4)) ^ (ra & 7);
        af[i] = *reinterpret_cast<const s16x8*>(As + ra * 64 + sa * 8);
        const int rb = wc * 64 + i * 16 + (lane & 15);
        const int sb = (kk * 4 + (lane >> 4)) ^ (rb & 7);
        bf[i] = *reinterpret_cast<const s16x8*>(Bs + rb * 64 + sb * 8);
      }
#pragma unroll
      for (int i = 0; i < 4; ++i)
#pragma unroll
        for (int jn = 0; jn < 4; ++jn)
          acc[i][jn] = __builtin_amdgcn_mfma_f32_16x16x32_bf16(af[i], bf[jn], acc[i][jn], 0, 0, 0);
    }
  }
  const int rg = (lane >> 4) * 4;
  const int cg = lane & 15;
#pragma unroll
  for (int i = 0; i < 4; ++i)
#pragma unroll
    for (int jn = 0; jn < 4; ++jn)
#pragma unroll
      for (int r = 0; r < 4; ++r) {
        const int rr = bm * 128 + wr * 64 + i * 16 + rg + r;
        const int cc = bn * 128 + wc * 64 + jn * 16 + cg;
        if (OUT_F32)
          reinterpret_cast<float*>(Cout)[(size_t)rr * N + cc] = acc[i][jn][r];
        else
          reinterpret_cast<__hip_bfloat16*>(Cout)[(size_t)rr * N + cc] =
              __float2bfloat16(acc[i][jn][r]);
      }
}

// ---------------- RoPE on Q and K (layout preserved [S][heads*DH]) ----------------
__global__ __launch_bounds__(256) void rope_kernel(const __hip_bfloat16* __restrict__ Qraw,
                                                   const __hip_bfloat16* __restrict__ Kraw,
                                                   const float* __restrict__ cosb,
                                                   const float* __restrict__ sinb,
                                                   __hip_bfloat16* __restrict__ Qro,
                                                   __hip_bfloat16* __restrict__ Kro) {
  const int s = blockIdx.x;
  const int tid = threadIdx.x;
  for (int idx = tid; idx < NH * DH; idx += 256) {
    const int d = idx & (DH - 1);
    const int hb = idx - d;
    float v = __bfloat162float(Qraw[(size_t)s * (NH * DH) + idx]);
    float o = (d < 64) ? -__bfloat162float(Qraw[(size_t)s * (NH * DH) + hb + d + 64])
                       : __bfloat162float(Qraw[(size_t)s * (NH * DH) + hb + d - 64]);
    float r = v * cosb[s * DH + d] + o * sinb[s * DH + d];
    Qro[(size_t)s * (NH * DH) + idx] = __float2bfloat16(r);
  }
  for (int idx = tid; idx < NKV * DH; idx += 256) {
    const int d = idx & (DH - 1);
    const int hb = idx - d;
    float v = __bfloat162float(Kraw[(size_t)s * (NKV * DH) + idx]);
    float o = (d < 64) ? -__bfloat162float(Kraw[(size_t)s * (NKV * DH) + hb + d + 64])
                       : __bfloat162float(Kraw[(size_t)s * (NKV * DH) + hb + d - 64]);
    float r = v * cosb[s * DH + d] + o * sinb[s * DH + d];
    Kro[(size_t)s * (NKV * DH) + idx] = __float2bfloat16(r);
  }
}

// ---------------- exact top-M key selection + sink/window, compacted ascending ----------------
__global__ __launch_bounds__(256) void select_kernel(const float* __restrict__ q_probs,
                                                     const float* __restrict__ v_norm,
                                                     const int* __restrict__ allowed,
                                                     const int* __restrict__ k_hard,
                                                     const int* __restrict__ sinkp,
                                                     const int* __restrict__ winp,
                                                     const int* __restrict__ Mp,
                                                     int* __restrict__ sel_idx,
                                                     int* __restrict__ sel_cnt) {
  const int h = blockIdx.x;
  const int tid = threadIdx.x;
  __shared__ float sc[S_LEN];
  __shared__ int part[256];
  for (int t = tid; t < S_LEN; t += 256) {
    float coll = 0.f;
#pragma unroll
    for (int l = 0; l < LTAB; ++l) {
      const int id = k_hard[(size_t)(h * LTAB + l) * S_LEN + t];
      coll += q_probs[(h * LTAB + l) * RBKT + id];
    }
    const bool al = allowed[h * S_LEN + t] != 0;
    sc[t] = al ? coll * v_norm[h * S_LEN + t] : -INFINITY;
  }
  __syncthreads();
  const int Mv = min(Mp[0], S_LEN);
  int sv = sinkp[0];
  sv = sv < 0 ? 0 : (sv > S_LEN ? S_LEN : sv);
  int wv = winp[0];
  wv = wv < 0 ? 0 : (wv > S_LEN ? S_LEN : wv);
  float st[8];
  int rk[8];
#pragma unroll
  for (int c = 0; c < 8; ++c) {
    st[c] = sc[tid * 8 + c];
    rk[c] = 0;
  }
  for (int u = 0; u < S_LEN; ++u) {
    const float su = sc[u];
#pragma unroll
    for (int c = 0; c < 8; ++c)
      rk[c] += (su > st[c]) || (su == st[c] && u < tid * 8 + c);  // stable top_k tie-break
  }
  bool selc[8];
  int cnt = 0;
#pragma unroll
  for (int c = 0; c < 8; ++c) {
    const int t = tid * 8 + c;
    bool sel = rk[c] < Mv;
    if (t < sv) sel = true;
    if (wv > 0) {
      int wstart = S_LEN - wv;
      if (wstart < sv) wstart = sv;
      if (t >= wstart) sel = true;
    }
    if (sv == 0 && wv == 0 && t == S_LEN - 1) sel = true;
    sel = sel && (allowed[h * S_LEN + t] != 0);
    selc[c] = sel;
    cnt += sel ? 1 : 0;
  }
  part[tid] = cnt;
  __syncthreads();
  if (tid == 0) {
    int run = 0;
    for (int i = 0; i < 256; ++i) {
      const int v = part[i];
      part[i] = run;
      run += v;
    }
    sel_cnt[h] = run;
  }
  __syncthreads();
  int off = part[tid];
#pragma unroll
  for (int c = 0; c < 8; ++c) {
    if (selc[c]) sel_idx[h * S_LEN + off++] = tid * 8 + c;
  }
}

// ---------------- flash attention over compacted key list ----------------
__global__ __launch_bounds__(256) void attn_kernel(const __hip_bfloat16* __restrict__ Qro,
                                                   const __hip_bfloat16* __restrict__ Kro,
                                                   const __hip_bfloat16* __restrict__ Vraw,
                                                   const int* __restrict__ sel_idx,
                                                   const int* __restrict__ sel_cnt,
                                                   __hip_bfloat16* __restrict__ ctx) {
  constexpr int BKV = 32;
  const int h = blockIdx.y;
  const int q0 = blockIdx.x * 64;
  const int tid = threadIdx.x, wid = tid >> 6, lane = tid & 63;
  const int kv = h >> 2;
  __shared__ __hip_bfloat16 Ks[BKV][DH + 8];   // [key][dim], padded vs bank conflicts
  __shared__ __hip_bfloat16 Vt[DH][BKV + 8];   // [dim][key] (transposed V)
  __shared__ __hip_bfloat16 Ps[4][16][BKV + 8];  // per-wave P tile [q][key]
  __shared__ int tIdx[BKV];
  const int qbase = q0 + wid * 16;
  s16x8 qf[4];
  {
    const __hip_bfloat16* qp =
        Qro + (size_t)(qbase + (lane & 15)) * (NH * DH) + h * DH + (lane >> 4) * 8;
#pragma unroll
    for (int kt = 0; kt < 4; ++kt) qf[kt] = *reinterpret_cast<const s16x8*>(qp + kt * 32);
  }
  float mr[4], lr[4];
#pragma unroll
  for (int r = 0; r < 4; ++r) {
    mr[r] = -3.0e38f;
    lr[r] = 0.f;
  }
  f32x4 o[8] = {};
  const int cnt = sel_cnt[h];
  const int qmax = q0 + 63;
  const float scaling = 0.08838834764831845f;  // 128^-0.5
  for (int j0 = 0; j0 < cnt; j0 += BKV) {
    if (sel_idx[h * S_LEN + j0] > qmax) break;  // ascending list: rest is masked
    const int nk = min(BKV, cnt - j0);
    __syncthreads();
    if (tid < BKV) tIdx[tid] = (tid < nk) ? sel_idx[h * S_LEN + j0 + tid] : 0x7fffffff;
#pragma unroll
    for (int c = 0; c < 2; ++c) {
      const int ch = tid + c * 256;
      const int row = ch >> 4, c8 = ch & 15;
      if (row < nk) {
        const int t = sel_idx[h * S_LEN + j0 + row];
        *reinterpret_cast<s16x8*>(&Ks[row][c8 * 8]) = *reinterpret_cast<const s16x8*>(
            Kro + (size_t)t * (NKV * DH) + kv * DH + c8 * 8);
      }
    }
    {
      const int j = tid >> 3;
      const int dp = (tid & 7) * 16;
      if (j < nk) {
        const int t = sel_idx[h * S_LEN + j0 + j];
        const __hip_bfloat16* vp = Vraw + (size_t)t * (NKV * DH) + kv * DH + dp;
#pragma unroll
        for (int i = 0; i < 16; ++i) Vt[dp + i][j] = vp[i];
      } else {
        const __hip_bfloat16 z = __float2bfloat16(0.f);
#pragma unroll
        for (int i = 0; i < 16; ++i) Vt[dp + i][j] = z;
      }
    }
    __syncthreads();
    // QK^T : D[q][key], two 16-key column tiles
    f32x4 s0 = {0.f, 0.f, 0.f, 0.f}, s1 = {0.f, 0.f, 0.f, 0.f};
#pragma unroll
    for (int kt = 0; kt < 4; ++kt) {
      s16x8 k0 = *reinterpret_cast<const s16x8*>(&Ks[lane & 15][kt * 32 + (lane >> 4) * 8]);
      s16x8 k1 = *reinterpret_cast<const s16x8*>(&Ks[16 + (lane & 15)][kt * 32 + (lane >> 4) * 8]);
      s0 = __builtin_amdgcn_mfma_f32_16x16x32_bf16(qf[kt], k0, s0, 0, 0, 0);
      s1 = __builtin_amdgcn_mfma_f32_16x16x32_bf16(qf[kt], k1, s1, 0, 0, 0);
    }
    const int t0 = tIdx[lane & 15];
    const int t1 = tIdx[16 + (lane & 15)];
#pragma unroll
    for (int r = 0; r < 4; ++r) {
      const int qs = qbase + ((lane >> 4) << 2) + r;
      const float v0 = (t0 <= qs) ? s0[r] * scaling : -1.0e9f;
      const float v1 = (t1 <= qs) ? s1[r] * scaling : -1.0e9f;
      float mx = fmaxf(v0, v1);
#pragma unroll
      for (int off = 1; off < 16; off <<= 1) mx = fmaxf(mx, __shfl_xor(mx, off));
      const float mn = fmaxf(mr[r], mx);
      const float scl = __expf(mr[r] - mn);
      const float p0 = __expf(v0 - mn);
      const float p1 = __expf(v1 - mn);
      float ps = p0 + p1;
#pragma unroll
      for (int off = 1; off < 16; off <<= 1) ps += __shfl_xor(ps, off);
      lr[r] = lr[r] * scl + ps;
      mr[r] = mn;
#pragma unroll
      for (int nt = 0; nt < 8; ++nt) o[nt][r] *= scl;
      Ps[wid][((lane >> 4) << 2) + r][lane & 15] = __float2bfloat16(p0);
      Ps[wid][((lane >> 4) << 2) + r][16 + (lane & 15)] = __float2bfloat16(p1);
    }
    __syncthreads();
    const s16x8 pf = *reinterpret_cast<const s16x8*>(&Ps[wid][lane & 15][(lane >> 4) * 8]);
#pragma unroll
    for (int nt = 0; nt < 8; ++nt) {
      const s16x8 vf =
          *reinterpret_cast<const s16x8*>(&Vt[nt * 16 + (lane & 15)][(lane >> 4) * 8]);
      o[nt] = __builtin_amdgcn_mfma_f32_16x16x32_bf16(pf, vf, o[nt], 0, 0, 0);
    }
  }
#pragma unroll
  for (int nt = 0; nt < 8; ++nt)
#pragma unroll
    for (int r = 0; r < 4; ++r) {
      const int qs = qbase + ((lane >> 4) << 2) + r;
      const int d = nt * 16 + (lane & 15);
      ctx[(size_t)qs * (NH * DH) + h * DH + d] = __float2bfloat16(o[nt][r] / lr[r]);
    }
}

}  // namespace

extern "C" void kernel_launch(void* const* d_in, const int* in_sizes, int n_in,
                              void* d_out, int out_size, void* d_ws, size_t ws_size,
                              hipStream_t stream) {
  const float* hidden = (const float*)d_in[0];
  const float* cosb = (const float*)d_in[1];
  const float* sinb = (const float*)d_in[2];
  const float* q_probs = (const float*)d_in[3];
  const float* v_norm = (const float*)d_in[4];
  const int* allowed = (const int*)d_in[5];
  const int* k_hard = (const int*)d_in[6];
  const float* Wq = (const float*)d_in[7];
  const float* Wk = (const float*)d_in[8];
  const float* Wv = (const float*)d_in[9];
  const float* Wo = (const float*)d_in[10];
  const int* sinkp = (const int*)d_in[11];
  const int* winp = (const int*)d_in[12];
  const int* Mp = (const int*)d_in[13];

  char* ws = (char*)d_ws;
  size_t off = 0;
  auto alloc = [&](size_t bytes) -> char* {
    char* p = ws + off;
    off += (bytes + 255) & ~(size_t)255;
    return p;
  };
  __hip_bfloat16* hbf = (__hip_bfloat16*)alloc((size_t)S_LEN * DM * 2);
  __hip_bfloat16* WqT = (__hip_bfloat16*)alloc((size_t)DM * DM * 2);
  __hip_bfloat16* WkT = (__hip_bfloat16*)alloc((size_t)(NKV * DH) * DM * 2);
  __hip_bfloat16* WvT = (__hip_bfloat16*)alloc((size_t)(NKV * DH) * DM * 2);
  __hip_bfloat16* WoT = (__hip_bfloat16*)alloc((size_t)DM * DM * 2);
  __hip_bfloat16* Qraw = (__hip_bfloat16*)alloc((size_t)S_LEN * NH * DH * 2);
  __hip_bfloat16* Kraw = (__hip_bfloat16*)alloc((size_t)S_LEN * NKV * DH * 2);
  __hip_bfloat16* Vraw = (__hip_bfloat16*)alloc((size_t)S_LEN * NKV * DH * 2);
  __hip_bfloat16* Qro = (__hip_bfloat16*)alloc((size_t)S_LEN * NH * DH * 2);
  __hip_bfloat16* Kro = (__hip_bfloat16*)alloc((size_t)S_LEN * NKV * DH * 2);
  __hip_bfloat16* ctx = (__hip_bfloat16*)alloc((size_t)S_LEN * NH * DH * 2);
  int* sel_idx = (int*)alloc((size_t)NH * S_LEN * 4);
  int* sel_cnt = (int*)alloc((size_t)NH * 4);
  if (off > ws_size) return;  // fail loudly via wrong output rather than corrupt memory

  {
    const int n4 = S_LEN * DM / 4;
    cvt_f32_bf16<<<(n4 + 255) / 256, 256, 0, stream>>>(hidden, hbf, n4);
  }
  dim3 tb(32, 8);
  transpose_cvt<<<dim3(DM / 32, DM / 32), tb, 0, stream>>>(Wq, WqT, DM, DM);
  transpose_cvt<<<dim3((NKV * DH) / 32, DM / 32), tb, 0, stream>>>(Wk, WkT, DM, NKV * DH);
  transpose_cvt<<<dim3((NKV * DH) / 32, DM / 32), tb, 0, stream>>>(Wv, WvT, DM, NKV * DH);
  transpose_cvt<<<dim3(DM / 32, DM / 32), tb, 0, stream>>>(Wo, WoT, DM, DM);

  gemm_bt<false><<<dim3((NH * DH) / 128, S_LEN / 128), 256, 0, stream>>>(
      hbf, WqT, (void*)Qraw, NH * DH, DM);
  gemm_bt<false><<<dim3((NKV * DH) / 128, S_LEN / 128), 256, 0, stream>>>(
      hbf, WkT, (void*)Kraw, NKV * DH, DM);
  gemm_bt<false><<<dim3((NKV * DH) / 128, S_LEN / 128), 256, 0, stream>>>(
      hbf, WvT, (void*)Vraw, NKV * DH, DM);

  rope_kernel<<<S_LEN, 256, 0, stream>>>(Qraw, Kraw, cosb, sinb, Qro, Kro);

  select_kernel<<<NH, 256, 0, stream>>>(q_probs, v_norm, allowed, k_hard, sinkp, winp, Mp,
                                        sel_idx, sel_cnt);

  attn_kernel<<<dim3(S_LEN / 64, NH), 256, 0, stream>>>(Qro, Kro, Vraw, sel_idx, sel_cnt, ctx);

  gemm_bt<true><<<dim3(DM / 128, S_LEN / 128), 256, 0, stream>>>(ctx, WoT, d_out, DM, DM);
}

// Round 2
// 573.673 us; speedup vs baseline: 2.1542x; 2.1542x over previous
//
#include <hip/hip_runtime.h>
#include <hip/hip_bf16.h>
#include <cstdint>
#include <cstddef>

namespace {

constexpr int S_LEN = 2048;
constexpr int DM    = 4096;
constexpr int NH    = 32;
constexpr int NKV   = 8;
constexpr int DH    = 128;
constexpr int LTAB  = 20;
constexpr int RBKT  = 128;

typedef short s16x8 __attribute__((ext_vector_type(8)));
typedef float f32x4 __attribute__((ext_vector_type(4)));
typedef unsigned long long u64;
struct u64x2 { u64 x, y; };

// ---------------- fp32 -> bf16 (flat) ----------------
__global__ __launch_bounds__(256) void cvt_f32_bf16(const float* __restrict__ in,
                                                    __hip_bfloat16* __restrict__ out,
                                                    int n4) {
  int i = blockIdx.x * blockDim.x + threadIdx.x;
  if (i >= n4) return;
  float4 v = reinterpret_cast<const float4*>(in)[i];
  __hip_bfloat16 a = __float2bfloat16(v.x);
  __hip_bfloat16 b = __float2bfloat16(v.y);
  __hip_bfloat16 c = __float2bfloat16(v.z);
  __hip_bfloat16 d = __float2bfloat16(v.w);
  ushort4 o;
  o.x = *reinterpret_cast<unsigned short*>(&a);
  o.y = *reinterpret_cast<unsigned short*>(&b);
  o.z = *reinterpret_cast<unsigned short*>(&c);
  o.w = *reinterpret_cast<unsigned short*>(&d);
  reinterpret_cast<ushort4*>(out)[i] = o;
}

// ---------------- transpose + convert: W[K][N] f32 -> Wt[N][K] bf16 ----------------
__global__ __launch_bounds__(256) void transpose_cvt(const float* __restrict__ W,
                                                     __hip_bfloat16* __restrict__ Wt,
                                                     int K, int N) {
  __shared__ float tile[32][33];
  const int kb = blockIdx.y * 32, nb = blockIdx.x * 32;
  const int tx = threadIdx.x, ty = threadIdx.y;
#pragma unroll
  for (int i = ty; i < 32; i += 8)
    tile[i][tx] = W[(size_t)(kb + i) * N + nb + tx];
  __syncthreads();
#pragma unroll
  for (int i = ty; i < 32; i += 8)
    Wt[(size_t)(nb + i) * K + kb + tx] = __float2bfloat16(tile[tx][i]);
}

// ---------------- bf16 GEMM: C[M][N] = A[M][K] * Bt[N][K]^T ----------------
// 128x128 tile, BK=64, 4 waves (2x2), mfma 16x16x32, swizzled global_load_lds staging.
template <bool OUT_F32>
__global__ __launch_bounds__(256) void gemm_bt(const __hip_bfloat16* __restrict__ A,
                                               const __hip_bfloat16* __restrict__ Bt,
                                               void* __restrict__ Cout,
                                               int N, int K) {
  __shared__ __hip_bfloat16 As[128 * 64];
  __shared__ __hip_bfloat16 Bs[128 * 64];
  const int tid = threadIdx.x;
  const int wid = tid >> 6;
  const int lane = tid & 63;
  const int bm = blockIdx.y, bn = blockIdx.x;
  const int wr = wid >> 1, wc = wid & 1;
  f32x4 acc[4][4] = {};
  const __hip_bfloat16* Abase = A + (size_t)bm * 128 * K;
  const __hip_bfloat16* Bbase = Bt + (size_t)bn * 128 * K;
  for (int kt = 0; kt < K; kt += 64) {
    __syncthreads();
#pragma unroll
    for (int j = 0; j < 4; ++j) {
      const int pb = j * 4096 + wid * 1024;  // wave-uniform LDS byte base
      const int p = pb + lane * 16;          // this lane's linear dest byte
      const int row = p >> 7;                // 0..127 (row = 128B of bf16, BK=64)
      const int slot = ((p >> 4) & 7) ^ (row & 7);  // inverse-swizzled source slot
      const int goff = row * K + kt + slot * 8;
      __builtin_amdgcn_global_load_lds(
          (const __attribute__((address_space(1))) void*)(Abase + goff),
          (__attribute__((address_space(3))) void*)(As + (pb >> 1)), 16, 0, 0);
      __builtin_amdgcn_global_load_lds(
          (const __attribute__((address_space(1))) void*)(Bbase + goff),
          (__attribute__((address_space(3))) void*)(Bs + (pb >> 1)), 16, 0, 0);
    }
    __syncthreads();
#pragma unroll
    for (int kk = 0; kk < 2; ++kk) {
      s16x8 af[4], bf[4];
#pragma unroll
      for (int i = 0; i < 4; ++i) {
        const int ra = wr * 64 + i * 16 + (lane & 15);
        const int sa = (kk * 4 + (lane >> 4)) ^ (ra & 7);
        af[i] = *reinterpret_cast<const s16x8*>(As + ra * 64 + sa * 8);
        const int rb = wc * 64 + i * 16 + (lane & 15);
        const int sb = (kk * 4 + (lane >> 4)) ^ (rb & 7);
        bf[i] = *reinterpret_cast<const s16x8*>(Bs + rb * 64 + sb * 8);
      }
#pragma unroll
      for (int i = 0; i < 4; ++i)
#pragma unroll
        for (int jn = 0; jn < 4; ++jn)
          acc[i][jn] = __builtin_amdgcn_mfma_f32_16x16x32_bf16(af[i], bf[jn], acc[i][jn], 0, 0, 0);
    }
  }
  const int rg = (lane >> 4) * 4;
  const int cg = lane & 15;
#pragma unroll
  for (int i = 0; i < 4; ++i)
#pragma unroll
    for (int jn = 0; jn < 4; ++jn)
#pragma unroll
      for (int r = 0; r < 4; ++r) {
        const int rr = bm * 128 + wr * 64 + i * 16 + rg + r;
        const int cc = bn * 128 + wc * 64 + jn * 16 + cg;
        if (OUT_F32)
          reinterpret_cast<float*>(Cout)[(size_t)rr * N + cc] = acc[i][jn][r];
        else
          reinterpret_cast<__hip_bfloat16*>(Cout)[(size_t)rr * N + cc] =
              __float2bfloat16(acc[i][jn][r]);
      }
}

// ---------------- RoPE on Q and K (layout preserved [S][heads*DH]) ----------------
__global__ __launch_bounds__(256) void rope_kernel(const __hip_bfloat16* __restrict__ Qraw,
                                                   const __hip_bfloat16* __restrict__ Kraw,
                                                   const float* __restrict__ cosb,
                                                   const float* __restrict__ sinb,
                                                   __hip_bfloat16* __restrict__ Qro,
                                                   __hip_bfloat16* __restrict__ Kro) {
  const int s = blockIdx.x;
  const int tid = threadIdx.x;
  for (int idx = tid; idx < NH * DH; idx += 256) {
    const int d = idx & (DH - 1);
    const int hb = idx - d;
    float v = __bfloat162float(Qraw[(size_t)s * (NH * DH) + idx]);
    float o = (d < 64) ? -__bfloat162float(Qraw[(size_t)s * (NH * DH) + hb + d + 64])
                       : __bfloat162float(Qraw[(size_t)s * (NH * DH) + hb + d - 64]);
    float r = v * cosb[s * DH + d] + o * sinb[s * DH + d];
    Qro[(size_t)s * (NH * DH) + idx] = __float2bfloat16(r);
  }
  for (int idx = tid; idx < NKV * DH; idx += 256) {
    const int d = idx & (DH - 1);
    const int hb = idx - d;
    float v = __bfloat162float(Kraw[(size_t)s * (NKV * DH) + idx]);
    float o = (d < 64) ? -__bfloat162float(Kraw[(size_t)s * (NKV * DH) + hb + d + 64])
                       : __bfloat162float(Kraw[(size_t)s * (NKV * DH) + hb + d - 64]);
    float r = v * cosb[s * DH + d] + o * sinb[s * DH + d];
    Kro[(size_t)s * (NKV * DH) + idx] = __float2bfloat16(r);
  }
}

// ---------------- exact top-M key selection + sink/window, compacted ascending -------
// 1024 threads/block, 1 block/head. Sortable u64 keys: (monotone(score)<<11)|(2047-t),
// all distinct -> rank = #{key_u > key_t}; select iff rank < M. Branchless u64 compares
// against LDS-broadcast keys (O(S^2) but dense pipelined VALU work).
__global__ __launch_bounds__(1024) void select_kernel(const float* __restrict__ q_probs,
                                                      const float* __restrict__ v_norm,
                                                      const int* __restrict__ allowed,
                                                      const int* __restrict__ k_hard,
                                                      const int* __restrict__ sinkp,
                                                      const int* __restrict__ winp,
                                                      const int* __restrict__ Mp,
                                                      int* __restrict__ sel_idx,
                                                      int* __restrict__ sel_cnt) {
  const int h = blockIdx.x;
  const int tid = threadIdx.x;
  const int lane = tid & 63;
  const int wid = tid >> 6;
  __shared__ u64 keys[S_LEN];
  __shared__ int waveTot[16];
  const int t0 = tid * 2;
  // ---- scores for candidates t0, t0+1 (sequential l-sum matches jnp .sum(axis=2)) ----
  float c0 = 0.f, c1 = 0.f;
#pragma unroll
  for (int l = 0; l < LTAB; ++l) {
    const int2 kh = *reinterpret_cast<const int2*>(&k_hard[(size_t)(h * LTAB + l) * S_LEN + t0]);
    c0 += q_probs[(h * LTAB + l) * RBKT + kh.x];
    c1 += q_probs[(h * LTAB + l) * RBKT + kh.y];
  }
  const int2 al = *reinterpret_cast<const int2*>(&allowed[h * S_LEN + t0]);
  const float2 vn = *reinterpret_cast<const float2*>(&v_norm[h * S_LEN + t0]);
  const float s0 = al.x ? c0 * vn.x : -INFINITY;
  const float s1 = al.y ? c1 * vn.y : -INFINITY;
  auto mkkey = [](float s, int t) -> u64 {
    unsigned m = __float_as_uint(s);
    m = (m & 0x80000000u) ? ~m : (m | 0x80000000u);
    return ((u64)m << 11) | (u64)(S_LEN - 1 - t);
  };
  const u64 k0 = mkkey(s0, t0);
  const u64 k1 = mkkey(s1, t0 + 1);
  keys[t0] = k0;
  keys[t0 + 1] = k1;
  __syncthreads();
  // ---- rank by counting (LDS broadcast reads, branchless) ----
  int r0 = 0, r1 = 0;
#pragma unroll 8
  for (int u = 0; u < S_LEN; u += 2) {
    const u64x2 kv = *reinterpret_cast<const u64x2*>(&keys[u]);
    r0 += (kv.x > k0) + (kv.y > k0);
    r1 += (kv.x > k1) + (kv.y > k1);
  }
  // ---- selection rules ----
  const int Mv = min(Mp[0], S_LEN);
  int sv = sinkp[0];
  sv = sv < 0 ? 0 : (sv > S_LEN ? S_LEN : sv);
  int wv = winp[0];
  wv = wv < 0 ? 0 : (wv > S_LEN ? S_LEN : wv);
  int wstart = S_LEN - wv;
  if (wstart < sv) wstart = sv;
  bool sel0 = r0 < Mv, sel1 = r1 < Mv;
  if (t0 < sv) sel0 = true;
  if (t0 + 1 < sv) sel1 = true;
  if (wv > 0) {
    if (t0 >= wstart) sel0 = true;
    if (t0 + 1 >= wstart) sel1 = true;
  }
  if (sv == 0 && wv == 0) {
    if (t0 == S_LEN - 1) sel0 = true;
    if (t0 + 1 == S_LEN - 1) sel1 = true;
  }
  sel0 = sel0 && (al.x != 0);
  sel1 = sel1 && (al.y != 0);
  const int cnt = (sel0 ? 1 : 0) + (sel1 ? 1 : 0);
  // ---- hierarchical exclusive scan (wave shfl + cross-wave LDS) ----
  int inc = cnt;
#pragma unroll
  for (int off = 1; off < 64; off <<= 1) {
    int n = __shfl_up(inc, off);
    if (lane >= off) inc += n;
  }
  if (lane == 63) waveTot[wid] = inc;
  __syncthreads();
  int wbase = 0;
  for (int w = 0; w < wid; ++w) wbase += waveTot[w];
  int pos = wbase + inc - cnt;
  if (tid == 0) {
    int tot = 0;
#pragma unroll
    for (int w = 0; w < 16; ++w) tot += waveTot[w];
    sel_cnt[h] = tot;
  }
  if (sel0) sel_idx[h * S_LEN + pos++] = t0;
  if (sel1) sel_idx[h * S_LEN + pos] = t0 + 1;
}

// ---------------- flash attention over compacted key list ----------------
__global__ __launch_bounds__(256) void attn_kernel(const __hip_bfloat16* __restrict__ Qro,
                                                   const __hip_bfloat16* __restrict__ Kro,
                                                   const __hip_bfloat16* __restrict__ Vraw,
                                                   const int* __restrict__ sel_idx,
                                                   const int* __restrict__ sel_cnt,
                                                   __hip_bfloat16* __restrict__ ctx) {
  constexpr int BKV = 32;
  const int h = blockIdx.y;
  const int q0 = blockIdx.x * 64;
  const int tid = threadIdx.x, wid = tid >> 6, lane = tid & 63;
  const int kv = h >> 2;
  __shared__ __hip_bfloat16 Ks[BKV][DH + 8];   // [key][dim], padded vs bank conflicts
  __shared__ __hip_bfloat16 Vt[DH][BKV + 8];   // [dim][key] (transposed V)
  __shared__ __hip_bfloat16 Ps[4][16][BKV + 8];  // per-wave P tile [q][key]
  __shared__ int tIdx[BKV];
  const int qbase = q0 + wid * 16;
  s16x8 qf[4];
  {
    const __hip_bfloat16* qp =
        Qro + (size_t)(qbase + (lane & 15)) * (NH * DH) + h * DH + (lane >> 4) * 8;
#pragma unroll
    for (int kt = 0; kt < 4; ++kt) qf[kt] = *reinterpret_cast<const s16x8*>(qp + kt * 32);
  }
  float mr[4], lr[4];
#pragma unroll
  for (int r = 0; r < 4; ++r) {
    mr[r] = -3.0e38f;
    lr[r] = 0.f;
  }
  f32x4 o[8] = {};
  const int cnt = sel_cnt[h];
  const int qmax = q0 + 63;
  const float scaling = 0.08838834764831845f;  // 128^-0.5
  for (int j0 = 0; j0 < cnt; j0 += BKV) {
    if (sel_idx[h * S_LEN + j0] > qmax) break;  // ascending list: rest is masked
    const int nk = min(BKV, cnt - j0);
    __syncthreads();
    if (tid < BKV) tIdx[tid] = (tid < nk) ? sel_idx[h * S_LEN + j0 + tid] : 0x7fffffff;
#pragma unroll
    for (int c = 0; c < 2; ++c) {
      const int ch = tid + c * 256;
      const int row = ch >> 4, c8 = ch & 15;
      if (row < nk) {
        const int t = sel_idx[h * S_LEN + j0 + row];
        *reinterpret_cast<s16x8*>(&Ks[row][c8 * 8]) = *reinterpret_cast<const s16x8*>(
            Kro + (size_t)t * (NKV * DH) + kv * DH + c8 * 8);
      }
    }
    {
      const int j = tid >> 3;
      const int dp = (tid & 7) * 16;
      if (j < nk) {
        const int t = sel_idx[h * S_LEN + j0 + j];
        const __hip_bfloat16* vp = Vraw + (size_t)t * (NKV * DH) + kv * DH + dp;
#pragma unroll
        for (int i = 0; i < 16; ++i) Vt[dp + i][j] = vp[i];
      } else {
        const __hip_bfloat16 z = __float2bfloat16(0.f);
#pragma unroll
        for (int i = 0; i < 16; ++i) Vt[dp + i][j] = z;
      }
    }
    __syncthreads();
    // QK^T : D[q][key], two 16-key column tiles
    f32x4 s0 = {0.f, 0.f, 0.f, 0.f}, s1 = {0.f, 0.f, 0.f, 0.f};
#pragma unroll
    for (int kt = 0; kt < 4; ++kt) {
      s16x8 k0 = *reinterpret_cast<const s16x8*>(&Ks[lane & 15][kt * 32 + (lane >> 4) * 8]);
      s16x8 k1 = *reinterpret_cast<const s16x8*>(&Ks[16 + (lane & 15)][kt * 32 + (lane >> 4) * 8]);
      s0 = __builtin_amdgcn_mfma_f32_16x16x32_bf16(qf[kt], k0, s0, 0, 0, 0);
      s1 = __builtin_amdgcn_mfma_f32_16x16x32_bf16(qf[kt], k1, s1, 0, 0, 0);
    }
    const int t0 = tIdx[lane & 15];
    const int t1 = tIdx[16 + (lane & 15)];
#pragma unroll
    for (int r = 0; r < 4; ++r) {
      const int qs = qbase + ((lane >> 4) << 2) + r;
      const float v0 = (t0 <= qs) ? s0[r] * scaling : -1.0e9f;
      const float v1 = (t1 <= qs) ? s1[r] * scaling : -1.0e9f;
      float mx = fmaxf(v0, v1);
#pragma unroll
      for (int off = 1; off < 16; off <<= 1) mx = fmaxf(mx, __shfl_xor(mx, off));
      const float mn = fmaxf(mr[r], mx);
      const float scl = __expf(mr[r] - mn);
      const float p0 = __expf(v0 - mn);
      const float p1 = __expf(v1 - mn);
      float ps = p0 + p1;
#pragma unroll
      for (int off = 1; off < 16; off <<= 1) ps += __shfl_xor(ps, off);
      lr[r] = lr[r] * scl + ps;
      mr[r] = mn;
#pragma unroll
      for (int nt = 0; nt < 8; ++nt) o[nt][r] *= scl;
      Ps[wid][((lane >> 4) << 2) + r][lane & 15] = __float2bfloat16(p0);
      Ps[wid][((lane >> 4) << 2) + r][16 + (lane & 15)] = __float2bfloat16(p1);
    }
    __syncthreads();
    const s16x8 pf = *reinterpret_cast<const s16x8*>(&Ps[wid][lane & 15][(lane >> 4) * 8]);
#pragma unroll
    for (int nt = 0; nt < 8; ++nt) {
      const s16x8 vf =
          *reinterpret_cast<const s16x8*>(&Vt[nt * 16 + (lane & 15)][(lane >> 4) * 8]);
      o[nt] = __builtin_amdgcn_mfma_f32_16x16x32_bf16(pf, vf, o[nt], 0, 0, 0);
    }
  }
#pragma unroll
  for (int nt = 0; nt < 8; ++nt)
#pragma unroll
    for (int r = 0; r < 4; ++r) {
      const int qs = qbase + ((lane >> 4) << 2) + r;
      const int d = nt * 16 + (lane & 15);
      ctx[(size_t)qs * (NH * DH) + h * DH + d] = __float2bfloat16(o[nt][r] / lr[r]);
    }
}

}  // namespace

extern "C" void kernel_launch(void* const* d_in, const int* in_sizes, int n_in,
                              void* d_out, int out_size, void* d_ws, size_t ws_size,
                              hipStream_t stream) {
  const float* hidden = (const float*)d_in[0];
  const float* cosb = (const float*)d_in[1];
  const float* sinb = (const float*)d_in[2];
  const float* q_probs = (const float*)d_in[3];
  const float* v_norm = (const float*)d_in[4];
  const int* allowed = (const int*)d_in[5];
  const int* k_hard = (const int*)d_in[6];
  const float* Wq = (const float*)d_in[7];
  const float* Wk = (const float*)d_in[8];
  const float* Wv = (const float*)d_in[9];
  const float* Wo = (const float*)d_in[10];
  const int* sinkp = (const int*)d_in[11];
  const int* winp = (const int*)d_in[12];
  const int* Mp = (const int*)d_in[13];

  char* ws = (char*)d_ws;
  size_t off = 0;
  auto alloc = [&](size_t bytes) -> char* {
    char* p = ws + off;
    off += (bytes + 255) & ~(size_t)255;
    return p;
  };
  __hip_bfloat16* hbf = (__hip_bfloat16*)alloc((size_t)S_LEN * DM * 2);
  __hip_bfloat16* WqT = (__hip_bfloat16*)alloc((size_t)DM * DM * 2);
  __hip_bfloat16* WkT = (__hip_bfloat16*)alloc((size_t)(NKV * DH) * DM * 2);
  __hip_bfloat16* WvT = (__hip_bfloat16*)alloc((size_t)(NKV * DH) * DM * 2);
  __hip_bfloat16* WoT = (__hip_bfloat16*)alloc((size_t)DM * DM * 2);
  __hip_bfloat16* Qraw = (__hip_bfloat16*)alloc((size_t)S_LEN * NH * DH * 2);
  __hip_bfloat16* Kraw = (__hip_bfloat16*)alloc((size_t)S_LEN * NKV * DH * 2);
  __hip_bfloat16* Vraw = (__hip_bfloat16*)alloc((size_t)S_LEN * NKV * DH * 2);
  __hip_bfloat16* Qro = (__hip_bfloat16*)alloc((size_t)S_LEN * NH * DH * 2);
  __hip_bfloat16* Kro = (__hip_bfloat16*)alloc((size_t)S_LEN * NKV * DH * 2);
  __hip_bfloat16* ctx = (__hip_bfloat16*)alloc((size_t)S_LEN * NH * DH * 2);
  int* sel_idx = (int*)alloc((size_t)NH * S_LEN * 4);
  int* sel_cnt = (int*)alloc((size_t)NH * 4);
  if (off > ws_size) return;  // fail loudly via wrong output rather than corrupt memory

  {
    const int n4 = S_LEN * DM / 4;
    cvt_f32_bf16<<<(n4 + 255) / 256, 256, 0, stream>>>(hidden, hbf, n4);
  }
  dim3 tb(32, 8);
  transpose_cvt<<<dim3(DM / 32, DM / 32), tb, 0, stream>>>(Wq, WqT, DM, DM);
  transpose_cvt<<<dim3((NKV * DH) / 32, DM / 32), tb, 0, stream>>>(Wk, WkT, DM, NKV * DH);
  transpose_cvt<<<dim3((NKV * DH) / 32, DM / 32), tb, 0, stream>>>(Wv, WvT, DM, NKV * DH);
  transpose_cvt<<<dim3(DM / 32, DM / 32), tb, 0, stream>>>(Wo, WoT, DM, DM);

  gemm_bt<false><<<dim3((NH * DH) / 128, S_LEN / 128), 256, 0, stream>>>(
      hbf, WqT, (void*)Qraw, NH * DH, DM);
  gemm_bt<false><<<dim3((NKV * DH) / 128, S_LEN / 128), 256, 0, stream>>>(
      hbf, WkT, (void*)Kraw, NKV * DH, DM);
  gemm_bt<false><<<dim3((NKV * DH) / 128, S_LEN / 128), 256, 0, stream>>>(
      hbf, WvT, (void*)Vraw, NKV * DH, DM);

  rope_kernel<<<S_LEN, 256, 0, stream>>>(Qraw, Kraw, cosb, sinb, Qro, Kro);

  select_kernel<<<NH, 1024, 0, stream>>>(q_probs, v_norm, allowed, k_hard, sinkp, winp, Mp,
                                         sel_idx, sel_cnt);

  attn_kernel<<<dim3(S_LEN / 64, NH), 256, 0, stream>>>(Qro, Kro, Vraw, sel_idx, sel_cnt, ctx);

  gemm_bt<true><<<dim3(DM / 128, S_LEN / 128), 256, 0, stream>>>(ctx, WoT, d_out, DM, DM);
}

// Round 3
// 431.173 us; speedup vs baseline: 2.8662x; 1.3305x over previous
//
#include <hip/hip_runtime.h>
#include <hip/hip_bf16.h>
#include <cstdint>
#include <cstddef>

namespace {

constexpr int S_LEN = 2048;
constexpr int DM    = 4096;
constexpr int NH    = 32;
constexpr int NKV   = 8;
constexpr int DH    = 128;
constexpr int LTAB  = 20;
constexpr int RBKT  = 128;
constexpr int NQKV  = NH * DH + 2 * NKV * DH;  // 6144 packed Q|K|V cols
constexpr int KOFF  = NH * DH;                 // 4096
constexpr int VOFF  = NH * DH + NKV * DH;      // 5120

typedef short s16x8 __attribute__((ext_vector_type(8)));
typedef float f32x4 __attribute__((ext_vector_type(4)));
typedef unsigned long long u64;
struct u64x2 { u64 x, y; };

__device__ inline short bf16s(float f) {
  __hip_bfloat16 b = __float2bfloat16(f);
  return (short)*reinterpret_cast<unsigned short*>(&b);
}
__device__ inline float s2f(short s) {
  unsigned short u = (unsigned short)s;
  return __bfloat162float(*reinterpret_cast<__hip_bfloat16*>(&u));
}

// ---------------- fp32 -> bf16 (flat) ----------------
__global__ __launch_bounds__(256) void cvt_f32_bf16(const float* __restrict__ in,
                                                    __hip_bfloat16* __restrict__ out,
                                                    int n4) {
  int i = blockIdx.x * blockDim.x + threadIdx.x;
  if (i >= n4) return;
  float4 v = reinterpret_cast<const float4*>(in)[i];
  ushort4 o;
  o.x = (unsigned short)bf16s(v.x);
  o.y = (unsigned short)bf16s(v.y);
  o.z = (unsigned short)bf16s(v.z);
  o.w = (unsigned short)bf16s(v.w);
  reinterpret_cast<ushort4*>(out)[i] = o;
}

// ------- transpose + convert: W[K][N] f32 -> Wt[N][K] bf16, 64x64 tiles, vectorized -------
__global__ __launch_bounds__(256) void transpose_cvt64(const float* __restrict__ W,
                                                       __hip_bfloat16* __restrict__ Wt,
                                                       int K, int N) {
  __shared__ float tile[64][65];
  const int kb = blockIdx.y * 64, nb = blockIdx.x * 64;
  const int tid = threadIdx.x;
  const int r0 = tid >> 4, c4 = (tid & 15) * 4;
#pragma unroll
  for (int it = 0; it < 4; ++it) {
    const int r = r0 + it * 16;
    float4 v = *reinterpret_cast<const float4*>(&W[(size_t)(kb + r) * N + nb + c4]);
    tile[r][c4] = v.x;
    tile[r][c4 + 1] = v.y;
    tile[r][c4 + 2] = v.z;
    tile[r][c4 + 3] = v.w;
  }
  __syncthreads();
  const int n0 = tid >> 4, k4 = (tid & 15) * 4;
#pragma unroll
  for (int it = 0; it < 4; ++it) {
    const int n = n0 + it * 16;
    ushort4 o;
    o.x = (unsigned short)bf16s(tile[k4][n]);
    o.y = (unsigned short)bf16s(tile[k4 + 1][n]);
    o.z = (unsigned short)bf16s(tile[k4 + 2][n]);
    o.w = (unsigned short)bf16s(tile[k4 + 3][n]);
    *reinterpret_cast<ushort4*>(&Wt[(size_t)(nb + n) * K + kb + k4]) = o;
  }
}

// ---------------- bf16 GEMM: C[M][N] = A[M][K] * Bt[N][K]^T ----------------
// 128x128 tile, BK=64, 4 waves (2x2), mfma 16x16x32, swizzled global_load_lds staging.
template <bool OUT_F32>
__global__ __launch_bounds__(256) void gemm_bt(const __hip_bfloat16* __restrict__ A,
                                               const __hip_bfloat16* __restrict__ Bt,
                                               void* __restrict__ Cout,
                                               int N, int K) {
  __shared__ __hip_bfloat16 As[128 * 64];
  __shared__ __hip_bfloat16 Bs[128 * 64];
  const int tid = threadIdx.x;
  const int wid = tid >> 6;
  const int lane = tid & 63;
  const int bm = blockIdx.y, bn = blockIdx.x;
  const int wr = wid >> 1, wc = wid & 1;
  f32x4 acc[4][4] = {};
  const __hip_bfloat16* Abase = A + (size_t)bm * 128 * K;
  const __hip_bfloat16* Bbase = Bt + (size_t)bn * 128 * K;
  for (int kt = 0; kt < K; kt += 64) {
    __syncthreads();
#pragma unroll
    for (int j = 0; j < 4; ++j) {
      const int pb = j * 4096 + wid * 1024;  // wave-uniform LDS byte base
      const int p = pb + lane * 16;          // this lane's linear dest byte
      const int row = p >> 7;                // 0..127 (row = 128B of bf16, BK=64)
      const int slot = ((p >> 4) & 7) ^ (row & 7);  // inverse-swizzled source slot
      const int goff = row * K + kt + slot * 8;
      __builtin_amdgcn_global_load_lds(
          (const __attribute__((address_space(1))) void*)(Abase + goff),
          (__attribute__((address_space(3))) void*)(As + (pb >> 1)), 16, 0, 0);
      __builtin_amdgcn_global_load_lds(
          (const __attribute__((address_space(1))) void*)(Bbase + goff),
          (__attribute__((address_space(3))) void*)(Bs + (pb >> 1)), 16, 0, 0);
    }
    __syncthreads();
#pragma unroll
    for (int kk = 0; kk < 2; ++kk) {
      s16x8 af[4], bf[4];
#pragma unroll
      for (int i = 0; i < 4; ++i) {
        const int ra = wr * 64 + i * 16 + (lane & 15);
        const int sa = (kk * 4 + (lane >> 4)) ^ (ra & 7);
        af[i] = *reinterpret_cast<const s16x8*>(As + ra * 64 + sa * 8);
        const int rb = wc * 64 + i * 16 + (lane & 15);
        const int sb = (kk * 4 + (lane >> 4)) ^ (rb & 7);
        bf[i] = *reinterpret_cast<const s16x8*>(Bs + rb * 64 + sb * 8);
      }
#pragma unroll
      for (int i = 0; i < 4; ++i)
#pragma unroll
        for (int jn = 0; jn < 4; ++jn)
          acc[i][jn] = __builtin_amdgcn_mfma_f32_16x16x32_bf16(af[i], bf[jn], acc[i][jn], 0, 0, 0);
    }
  }
  const int rg = (lane >> 4) * 4;
  const int cg = lane & 15;
#pragma unroll
  for (int i = 0; i < 4; ++i)
#pragma unroll
    for (int jn = 0; jn < 4; ++jn)
#pragma unroll
      for (int r = 0; r < 4; ++r) {
        const int rr = bm * 128 + wr * 64 + i * 16 + rg + r;
        const int cc = bn * 128 + wc * 64 + jn * 16 + cg;
        if (OUT_F32)
          reinterpret_cast<float*>(Cout)[(size_t)rr * N + cc] = acc[i][jn][r];
        else
          reinterpret_cast<__hip_bfloat16*>(Cout)[(size_t)rr * N + cc] =
              __float2bfloat16(acc[i][jn][r]);
      }
}

// ---------------- RoPE on packed QKV -> Qro [S][4096], Kro [S][1024] ----------------
__global__ __launch_bounds__(256) void rope_kernel(const __hip_bfloat16* __restrict__ QKV,
                                                   const float* __restrict__ cosb,
                                                   const float* __restrict__ sinb,
                                                   __hip_bfloat16* __restrict__ Qro,
                                                   __hip_bfloat16* __restrict__ Kro) {
  const int s = blockIdx.x;
  const int tid = threadIdx.x;
  const float* cs = cosb + s * DH;
  const float* sn = sinb + s * DH;
  const __hip_bfloat16* row = QKV + (size_t)s * NQKV;
  for (int ch = tid; ch < 512 + 128; ch += 256) {
    const bool isQ = ch < 512;
    const int idx8 = (isQ ? ch : ch - 512) * 8;
    const int d8 = idx8 & (DH - 1);
    const int hb = idx8 - d8;
    const __hip_bfloat16* src = isQ ? row : row + KOFF;
    s16x8 v = *reinterpret_cast<const s16x8*>(src + idx8);
    s16x8 p = *reinterpret_cast<const s16x8*>(src + hb + (d8 ^ 64));
    const float sgn = (d8 < 64) ? -1.f : 1.f;
    s16x8 outv;
#pragma unroll
    for (int j = 0; j < 8; ++j) {
      const float r = s2f(v[j]) * cs[d8 + j] + sgn * s2f(p[j]) * sn[d8 + j];
      outv[j] = bf16s(r);
    }
    if (isQ)
      *reinterpret_cast<s16x8*>(Qro + (size_t)s * (NH * DH) + idx8) = outv;
    else
      *reinterpret_cast<s16x8*>(Kro + (size_t)s * (NKV * DH) + idx8) = outv;
  }
}

// ---------------- exact top-M key selection + sink/window, compacted ascending -------
__global__ __launch_bounds__(1024) void select_kernel(const float* __restrict__ q_probs,
                                                      const float* __restrict__ v_norm,
                                                      const int* __restrict__ allowed,
                                                      const int* __restrict__ k_hard,
                                                      const int* __restrict__ sinkp,
                                                      const int* __restrict__ winp,
                                                      const int* __restrict__ Mp,
                                                      int* __restrict__ sel_idx,
                                                      int* __restrict__ sel_cnt) {
  const int h = blockIdx.x;
  const int tid = threadIdx.x;
  const int lane = tid & 63;
  const int wid = tid >> 6;
  __shared__ u64 keys[S_LEN];
  __shared__ int waveTot[16];
  const int t0 = tid * 2;
  float c0 = 0.f, c1 = 0.f;
#pragma unroll
  for (int l = 0; l < LTAB; ++l) {
    const int2 kh = *reinterpret_cast<const int2*>(&k_hard[(size_t)(h * LTAB + l) * S_LEN + t0]);
    c0 += q_probs[(h * LTAB + l) * RBKT + kh.x];
    c1 += q_probs[(h * LTAB + l) * RBKT + kh.y];
  }
  const int2 al = *reinterpret_cast<const int2*>(&allowed[h * S_LEN + t0]);
  const float2 vn = *reinterpret_cast<const float2*>(&v_norm[h * S_LEN + t0]);
  const float s0 = al.x ? c0 * vn.x : -INFINITY;
  const float s1 = al.y ? c1 * vn.y : -INFINITY;
  auto mkkey = [](float s, int t) -> u64 {
    unsigned m = __float_as_uint(s);
    m = (m & 0x80000000u) ? ~m : (m | 0x80000000u);
    return ((u64)m << 11) | (u64)(S_LEN - 1 - t);
  };
  const u64 k0 = mkkey(s0, t0);
  const u64 k1 = mkkey(s1, t0 + 1);
  keys[t0] = k0;
  keys[t0 + 1] = k1;
  __syncthreads();
  int r0 = 0, r1 = 0;
#pragma unroll 8
  for (int u = 0; u < S_LEN; u += 2) {
    const u64x2 kv = *reinterpret_cast<const u64x2*>(&keys[u]);
    r0 += (kv.x > k0) + (kv.y > k0);
    r1 += (kv.x > k1) + (kv.y > k1);
  }
  const int Mv = min(Mp[0], S_LEN);
  int sv = sinkp[0];
  sv = sv < 0 ? 0 : (sv > S_LEN ? S_LEN : sv);
  int wv = winp[0];
  wv = wv < 0 ? 0 : (wv > S_LEN ? S_LEN : wv);
  int wstart = S_LEN - wv;
  if (wstart < sv) wstart = sv;
  bool sel0 = r0 < Mv, sel1 = r1 < Mv;
  if (t0 < sv) sel0 = true;
  if (t0 + 1 < sv) sel1 = true;
  if (wv > 0) {
    if (t0 >= wstart) sel0 = true;
    if (t0 + 1 >= wstart) sel1 = true;
  }
  if (sv == 0 && wv == 0) {
    if (t0 == S_LEN - 1) sel0 = true;
    if (t0 + 1 == S_LEN - 1) sel1 = true;
  }
  sel0 = sel0 && (al.x != 0);
  sel1 = sel1 && (al.y != 0);
  const int cnt = (sel0 ? 1 : 0) + (sel1 ? 1 : 0);
  int inc = cnt;
#pragma unroll
  for (int off = 1; off < 64; off <<= 1) {
    int n = __shfl_up(inc, off);
    if (lane >= off) inc += n;
  }
  if (lane == 63) waveTot[wid] = inc;
  __syncthreads();
  int wbase = 0;
  for (int w = 0; w < wid; ++w) wbase += waveTot[w];
  int pos = wbase + inc - cnt;
  if (tid == 0) {
    int tot = 0;
#pragma unroll
    for (int w = 0; w < 16; ++w) tot += waveTot[w];
    sel_cnt[h] = tot;
  }
  if (sel0) sel_idx[h * S_LEN + pos++] = t0;
  if (sel1) sel_idx[h * S_LEN + pos] = t0 + 1;
}

// ---------------- flash attention over compacted key list ----------------
__global__ __launch_bounds__(256) void attn_kernel(const __hip_bfloat16* __restrict__ Qro,
                                                   const __hip_bfloat16* __restrict__ Kro,
                                                   const __hip_bfloat16* __restrict__ Vpk,
                                                   const int* __restrict__ sel_idx,
                                                   const int* __restrict__ sel_cnt,
                                                   __hip_bfloat16* __restrict__ ctx) {
  constexpr int BKV = 32;
  const int h = blockIdx.y;
  const int q0 = blockIdx.x * 64;
  const int tid = threadIdx.x, wid = tid >> 6, lane = tid & 63;
  const int kv = h >> 2;
  __shared__ __hip_bfloat16 Ks[BKV][DH + 8];
  __shared__ __hip_bfloat16 Vt[DH][BKV + 8];
  __shared__ __hip_bfloat16 Ps[4][16][BKV + 8];
  __shared__ int tIdx[BKV];
  const int qbase = q0 + wid * 16;
  const float scaling = 0.08838834764831845f;  // 128^-0.5 (pre-applied to Q)
  s16x8 qf[4];
  {
    const __hip_bfloat16* qp =
        Qro + (size_t)(qbase + (lane & 15)) * (NH * DH) + h * DH + (lane >> 4) * 8;
#pragma unroll
    for (int kt = 0; kt < 4; ++kt) {
      s16x8 q = *reinterpret_cast<const s16x8*>(qp + kt * 32);
#pragma unroll
      for (int j = 0; j < 8; ++j) q[j] = bf16s(s2f(q[j]) * scaling);
      qf[kt] = q;
    }
  }
  float mr[4], lr[4];
#pragma unroll
  for (int r = 0; r < 4; ++r) {
    mr[r] = -3.0e38f;
    lr[r] = 0.f;
  }
  f32x4 o[8] = {};
  const int cnt = sel_cnt[h];
  const int qmax = q0 + 63;
  for (int j0 = 0; j0 < cnt; j0 += BKV) {
    if (sel_idx[h * S_LEN + j0] > qmax) break;  // ascending list: rest is masked
    const int nk = min(BKV, cnt - j0);
    __syncthreads();
    if (tid < BKV) tIdx[tid] = (tid < nk) ? sel_idx[h * S_LEN + j0 + tid] : 0x7fffffff;
#pragma unroll
    for (int c = 0; c < 2; ++c) {
      const int ch = tid + c * 256;
      const int row = ch >> 4, c8 = ch & 15;
      if (row < nk) {
        const int t = sel_idx[h * S_LEN + j0 + row];
        *reinterpret_cast<s16x8*>(&Ks[row][c8 * 8]) = *reinterpret_cast<const s16x8*>(
            Kro + (size_t)t * (NKV * DH) + kv * DH + c8 * 8);
      }
    }
    {
      const int j = tid >> 3;            // key slot 0..31
      const int dp = (tid & 7) * 16;     // dim chunk
      if (j < nk) {
        const int t = sel_idx[h * S_LEN + j0 + j];
        const __hip_bfloat16* vp = Vpk + (size_t)t * NQKV + kv * DH + dp;
        s16x8 a = *reinterpret_cast<const s16x8*>(vp);
        s16x8 b = *reinterpret_cast<const s16x8*>(vp + 8);
#pragma unroll
        for (int i = 0; i < 8; ++i) reinterpret_cast<short&>(Vt[dp + i][j]) = a[i];
#pragma unroll
        for (int i = 0; i < 8; ++i) reinterpret_cast<short&>(Vt[dp + 8 + i][j]) = b[i];
      } else {
#pragma unroll
        for (int i = 0; i < 16; ++i) reinterpret_cast<short&>(Vt[dp + i][j]) = 0;
      }
    }
    __syncthreads();
    // QK^T : D[q][key], two 16-key column tiles
    f32x4 s0 = {0.f, 0.f, 0.f, 0.f}, s1 = {0.f, 0.f, 0.f, 0.f};
#pragma unroll
    for (int kt = 0; kt < 4; ++kt) {
      s16x8 k0 = *reinterpret_cast<const s16x8*>(&Ks[lane & 15][kt * 32 + (lane >> 4) * 8]);
      s16x8 k1 = *reinterpret_cast<const s16x8*>(&Ks[16 + (lane & 15)][kt * 32 + (lane >> 4) * 8]);
      s0 = __builtin_amdgcn_mfma_f32_16x16x32_bf16(qf[kt], k0, s0, 0, 0, 0);
      s1 = __builtin_amdgcn_mfma_f32_16x16x32_bf16(qf[kt], k1, s1, 0, 0, 0);
    }
    const int t0 = tIdx[lane & 15];
    const int t1 = tIdx[16 + (lane & 15)];
    float v0[4], v1[4], mx[4];
    bool need = false;
#pragma unroll
    for (int r = 0; r < 4; ++r) {
      const int qs = qbase + ((lane >> 4) << 2) + r;
      v0[r] = (t0 <= qs) ? s0[r] : -1.0e9f;
      v1[r] = (t1 <= qs) ? s1[r] : -1.0e9f;
      float m = fmaxf(v0[r], v1[r]);
#pragma unroll
      for (int off = 1; off < 16; off <<= 1) m = fmaxf(m, __shfl_xor(m, off));
      mx[r] = m;
      need = need || (m > mr[r] + 8.f);
    }
    if (__any(need)) {  // T13 defer-max: skip O-rescale when max growth small
#pragma unroll
      for (int r = 0; r < 4; ++r) {
        const float mn = fmaxf(mr[r], mx[r]);
        const float scl = __expf(mr[r] - mn);
        lr[r] *= scl;
#pragma unroll
        for (int nt = 0; nt < 8; ++nt) o[nt][r] *= scl;
        mr[r] = mn;
      }
    }
#pragma unroll
    for (int r = 0; r < 4; ++r) {
      const float p0 = __expf(v0[r] - mr[r]);
      const float p1 = __expf(v1[r] - mr[r]);
      float ps = p0 + p1;
#pragma unroll
      for (int off = 1; off < 16; off <<= 1) ps += __shfl_xor(ps, off);
      lr[r] += ps;
      Ps[wid][((lane >> 4) << 2) + r][lane & 15] = __float2bfloat16(p0);
      Ps[wid][((lane >> 4) << 2) + r][16 + (lane & 15)] = __float2bfloat16(p1);
    }
    const s16x8 pf = *reinterpret_cast<const s16x8*>(&Ps[wid][lane & 15][(lane >> 4) * 8]);
#pragma unroll
    for (int nt = 0; nt < 8; ++nt) {
      const s16x8 vf =
          *reinterpret_cast<const s16x8*>(&Vt[nt * 16 + (lane & 15)][(lane >> 4) * 8]);
      o[nt] = __builtin_amdgcn_mfma_f32_16x16x32_bf16(pf, vf, o[nt], 0, 0, 0);
    }
  }
#pragma unroll
  for (int nt = 0; nt < 8; ++nt)
#pragma unroll
    for (int r = 0; r < 4; ++r) {
      const int qs = qbase + ((lane >> 4) << 2) + r;
      const int d = nt * 16 + (lane & 15);
      ctx[(size_t)qs * (NH * DH) + h * DH + d] = __float2bfloat16(o[nt][r] / lr[r]);
    }
}

}  // namespace

extern "C" void kernel_launch(void* const* d_in, const int* in_sizes, int n_in,
                              void* d_out, int out_size, void* d_ws, size_t ws_size,
                              hipStream_t stream) {
  const float* hidden = (const float*)d_in[0];
  const float* cosb = (const float*)d_in[1];
  const float* sinb = (const float*)d_in[2];
  const float* q_probs = (const float*)d_in[3];
  const float* v_norm = (const float*)d_in[4];
  const int* allowed = (const int*)d_in[5];
  const int* k_hard = (const int*)d_in[6];
  const float* Wq = (const float*)d_in[7];
  const float* Wk = (const float*)d_in[8];
  const float* Wv = (const float*)d_in[9];
  const float* Wo = (const float*)d_in[10];
  const int* sinkp = (const int*)d_in[11];
  const int* winp = (const int*)d_in[12];
  const int* Mp = (const int*)d_in[13];

  char* ws = (char*)d_ws;
  size_t off = 0;
  auto alloc = [&](size_t bytes) -> char* {
    char* p = ws + off;
    off += (bytes + 255) & ~(size_t)255;
    return p;
  };
  __hip_bfloat16* hbf = (__hip_bfloat16*)alloc((size_t)S_LEN * DM * 2);
  __hip_bfloat16* WqkvT = (__hip_bfloat16*)alloc((size_t)NQKV * DM * 2);  // packed [6144][4096]
  __hip_bfloat16* WoT = (__hip_bfloat16*)alloc((size_t)DM * DM * 2);
  __hip_bfloat16* QKV = (__hip_bfloat16*)alloc((size_t)S_LEN * NQKV * 2);
  __hip_bfloat16* Qro = (__hip_bfloat16*)alloc((size_t)S_LEN * NH * DH * 2);
  __hip_bfloat16* Kro = (__hip_bfloat16*)alloc((size_t)S_LEN * NKV * DH * 2);
  __hip_bfloat16* ctx = (__hip_bfloat16*)alloc((size_t)S_LEN * NH * DH * 2);
  int* sel_idx = (int*)alloc((size_t)NH * S_LEN * 4);
  int* sel_cnt = (int*)alloc((size_t)NH * 4);
  if (off > ws_size) return;

  {
    const int n4 = S_LEN * DM / 4;
    cvt_f32_bf16<<<(n4 + 255) / 256, 256, 0, stream>>>(hidden, hbf, n4);
  }
  // transposes into the packed QKV weight + WoT
  transpose_cvt64<<<dim3(DM / 64, DM / 64), 256, 0, stream>>>(Wq, WqkvT, DM, DM);
  transpose_cvt64<<<dim3((NKV * DH) / 64, DM / 64), 256, 0, stream>>>(
      Wk, WqkvT + (size_t)KOFF * DM, DM, NKV * DH);
  transpose_cvt64<<<dim3((NKV * DH) / 64, DM / 64), 256, 0, stream>>>(
      Wv, WqkvT + (size_t)VOFF * DM, DM, NKV * DH);
  transpose_cvt64<<<dim3(DM / 64, DM / 64), 256, 0, stream>>>(Wo, WoT, DM, DM);

  // fused QKV projection: [2048][4096] x [6144][4096]^T -> [2048][6144]
  gemm_bt<false><<<dim3(NQKV / 128, S_LEN / 128), 256, 0, stream>>>(
      hbf, WqkvT, (void*)QKV, NQKV, DM);

  rope_kernel<<<S_LEN, 256, 0, stream>>>(QKV, cosb, sinb, Qro, Kro);

  select_kernel<<<NH, 1024, 0, stream>>>(q_probs, v_norm, allowed, k_hard, sinkp, winp, Mp,
                                         sel_idx, sel_cnt);

  attn_kernel<<<dim3(S_LEN / 64, NH), 256, 0, stream>>>(Qro, Kro, QKV + VOFF, sel_idx,
                                                        sel_cnt, ctx);

  gemm_bt<true><<<dim3(DM / 128, S_LEN / 128), 256, 0, stream>>>(ctx, WoT, d_out, DM, DM);
}

// Round 5
// 422.684 us; speedup vs baseline: 2.9238x; 1.0201x over previous
//
#include <hip/hip_runtime.h>
#include <hip/hip_bf16.h>
#include <cstdint>
#include <cstddef>

namespace {

constexpr int S_LEN = 2048;
constexpr int DM    = 4096;
constexpr int NH    = 32;
constexpr int NKV   = 8;
constexpr int DH    = 128;
constexpr int LTAB  = 20;
constexpr int RBKT  = 128;
constexpr int NQKV  = NH * DH + 2 * NKV * DH;  // 6144 packed Q|K|V cols
constexpr int KOFF  = NH * DH;                 // 4096
constexpr int VOFF  = NH * DH + NKV * DH;      // 5120

typedef short s16x8 __attribute__((ext_vector_type(8)));
typedef float f32x4 __attribute__((ext_vector_type(4)));
typedef unsigned long long u64;
struct u64x2 { u64 x, y; };

__device__ inline short bf16s(float f) {
  __hip_bfloat16 b = __float2bfloat16(f);
  return (short)*reinterpret_cast<unsigned short*>(&b);
}
__device__ inline float s2f(short s) {
  unsigned short u = (unsigned short)s;
  return __bfloat162float(*reinterpret_cast<__hip_bfloat16*>(&u));
}

// ---------------- fp32 -> bf16 (flat) ----------------
__global__ __launch_bounds__(256) void cvt_f32_bf16(const float* __restrict__ in,
                                                    __hip_bfloat16* __restrict__ out,
                                                    int n4) {
  int i = blockIdx.x * blockDim.x + threadIdx.x;
  if (i >= n4) return;
  float4 v = reinterpret_cast<const float4*>(in)[i];
  ushort4 o;
  o.x = (unsigned short)bf16s(v.x);
  o.y = (unsigned short)bf16s(v.y);
  o.z = (unsigned short)bf16s(v.z);
  o.w = (unsigned short)bf16s(v.w);
  reinterpret_cast<ushort4*>(out)[i] = o;
}

// ------- transpose + convert: W[K][N] f32 -> Wt[N][K] bf16, 64x64 tiles, vectorized -------
__global__ __launch_bounds__(256) void transpose_cvt64(const float* __restrict__ W,
                                                       __hip_bfloat16* __restrict__ Wt,
                                                       int K, int N) {
  __shared__ float tile[64][65];
  const int kb = blockIdx.y * 64, nb = blockIdx.x * 64;
  const int tid = threadIdx.x;
  const int r0 = tid >> 4, c4 = (tid & 15) * 4;
#pragma unroll
  for (int it = 0; it < 4; ++it) {
    const int r = r0 + it * 16;
    float4 v = *reinterpret_cast<const float4*>(&W[(size_t)(kb + r) * N + nb + c4]);
    tile[r][c4] = v.x;
    tile[r][c4 + 1] = v.y;
    tile[r][c4 + 2] = v.z;
    tile[r][c4 + 3] = v.w;
  }
  __syncthreads();
  const int n0 = tid >> 4, k4 = (tid & 15) * 4;
#pragma unroll
  for (int it = 0; it < 4; ++it) {
    const int n = n0 + it * 16;
    ushort4 o;
    o.x = (unsigned short)bf16s(tile[k4][n]);
    o.y = (unsigned short)bf16s(tile[k4 + 1][n]);
    o.z = (unsigned short)bf16s(tile[k4 + 2][n]);
    o.w = (unsigned short)bf16s(tile[k4 + 3][n]);
    *reinterpret_cast<ushort4*>(&Wt[(size_t)(nb + n) * K + kb + k4]) = o;
  }
}

// ---------------- bf16 GEMM: C[M][N] = A[M][K] * Bt[N][K]^T ----------------
// 128x128 tile, BK=64, 4 waves (2x2), mfma 16x16x32, swizzled global_load_lds staging.
// T1: XCD-aware chunked blockIdx swizzle (bijective when nwg % 8 == 0).
template <bool OUT_F32>
__global__ __launch_bounds__(256) void gemm_bt(const __hip_bfloat16* __restrict__ A,
                                               const __hip_bfloat16* __restrict__ Bt,
                                               void* __restrict__ Cout,
                                               int N, int K) {
  __shared__ __hip_bfloat16 As[128 * 64];
  __shared__ __hip_bfloat16 Bs[128 * 64];
  const int tid = threadIdx.x;
  const int wid = tid >> 6;
  const int lane = tid & 63;
  int bm, bn;
  {
    const int nwg = gridDim.x * gridDim.y;
    const int orig = blockIdx.y * gridDim.x + blockIdx.x;
    if ((nwg & 7) == 0) {
      const int cpx = nwg >> 3;
      const int id2 = (orig & 7) * cpx + (orig >> 3);
      bm = id2 / gridDim.x;
      bn = id2 % gridDim.x;
    } else {
      bm = blockIdx.y;
      bn = blockIdx.x;
    }
  }
  const int wr = wid >> 1, wc = wid & 1;
  f32x4 acc[4][4] = {};
  const __hip_bfloat16* Abase = A + (size_t)bm * 128 * K;
  const __hip_bfloat16* Bbase = Bt + (size_t)bn * 128 * K;
  for (int kt = 0; kt < K; kt += 64) {
    __syncthreads();
#pragma unroll
    for (int j = 0; j < 4; ++j) {
      const int pb = j * 4096 + wid * 1024;  // wave-uniform LDS byte base
      const int p = pb + lane * 16;          // this lane's linear dest byte
      const int row = p >> 7;                // 0..127 (row = 128B of bf16, BK=64)
      const int slot = ((p >> 4) & 7) ^ (row & 7);  // inverse-swizzled source slot
      const int goff = row * K + kt + slot * 8;
      __builtin_amdgcn_global_load_lds(
          (const __attribute__((address_space(1))) void*)(Abase + goff),
          (__attribute__((address_space(3))) void*)(As + (pb >> 1)), 16, 0, 0);
      __builtin_amdgcn_global_load_lds(
          (const __attribute__((address_space(1))) void*)(Bbase + goff),
          (__attribute__((address_space(3))) void*)(Bs + (pb >> 1)), 16, 0, 0);
    }
    __syncthreads();
#pragma unroll
    for (int kk = 0; kk < 2; ++kk) {
      s16x8 af[4], bf[4];
#pragma unroll
      for (int i = 0; i < 4; ++i) {
        const int ra = wr * 64 + i * 16 + (lane & 15);
        const int sa = (kk * 4 + (lane >> 4)) ^ (ra & 7);
        af[i] = *reinterpret_cast<const s16x8*>(As + ra * 64 + sa * 8);
        const int rb = wc * 64 + i * 16 + (lane & 15);
        const int sb = (kk * 4 + (lane >> 4)) ^ (rb & 7);
        bf[i] = *reinterpret_cast<const s16x8*>(Bs + rb * 64 + sb * 8);
      }
#pragma unroll
      for (int i = 0; i < 4; ++i)
#pragma unroll
        for (int jn = 0; jn < 4; ++jn)
          acc[i][jn] = __builtin_amdgcn_mfma_f32_16x16x32_bf16(af[i], bf[jn], acc[i][jn], 0, 0, 0);
    }
  }
  const int rg = (lane >> 4) * 4;
  const int cg = lane & 15;
#pragma unroll
  for (int i = 0; i < 4; ++i)
#pragma unroll
    for (int jn = 0; jn < 4; ++jn)
#pragma unroll
      for (int r = 0; r < 4; ++r) {
        const int rr = bm * 128 + wr * 64 + i * 16 + rg + r;
        const int cc = bn * 128 + wc * 64 + jn * 16 + cg;
        if (OUT_F32)
          reinterpret_cast<float*>(Cout)[(size_t)rr * N + cc] = acc[i][jn][r];
        else
          reinterpret_cast<__hip_bfloat16*>(Cout)[(size_t)rr * N + cc] =
              __float2bfloat16(acc[i][jn][r]);
      }
}

// ---------------- RoPE on packed QKV -> Qro [S][4096], Kro [S][1024] ----------------
__global__ __launch_bounds__(256) void rope_kernel(const __hip_bfloat16* __restrict__ QKV,
                                                   const float* __restrict__ cosb,
                                                   const float* __restrict__ sinb,
                                                   __hip_bfloat16* __restrict__ Qro,
                                                   __hip_bfloat16* __restrict__ Kro) {
  const int s = blockIdx.x;
  const int tid = threadIdx.x;
  const float* cs = cosb + s * DH;
  const float* sn = sinb + s * DH;
  const __hip_bfloat16* row = QKV + (size_t)s * NQKV;
  for (int ch = tid; ch < 512 + 128; ch += 256) {
    const bool isQ = ch < 512;
    const int idx8 = (isQ ? ch : ch - 512) * 8;
    const int d8 = idx8 & (DH - 1);
    const int hb = idx8 - d8;
    const __hip_bfloat16* src = isQ ? row : row + KOFF;
    s16x8 v = *reinterpret_cast<const s16x8*>(src + idx8);
    s16x8 p = *reinterpret_cast<const s16x8*>(src + hb + (d8 ^ 64));
    const float sgn = (d8 < 64) ? -1.f : 1.f;
    s16x8 outv;
#pragma unroll
    for (int j = 0; j < 8; ++j) {
      const float r = s2f(v[j]) * cs[d8 + j] + sgn * s2f(p[j]) * sn[d8 + j];
      outv[j] = bf16s(r);
    }
    if (isQ)
      *reinterpret_cast<s16x8*>(Qro + (size_t)s * (NH * DH) + idx8) = outv;
    else
      *reinterpret_cast<s16x8*>(Kro + (size_t)s * (NKV * DH) + idx8) = outv;
  }
}

// ---------------- exact top-M key selection + sink/window, compacted ascending -------
__global__ __launch_bounds__(1024) void select_kernel(const float* __restrict__ q_probs,
                                                      const float* __restrict__ v_norm,
                                                      const int* __restrict__ allowed,
                                                      const int* __restrict__ k_hard,
                                                      const int* __restrict__ sinkp,
                                                      const int* __restrict__ winp,
                                                      const int* __restrict__ Mp,
                                                      int* __restrict__ sel_idx,
                                                      int* __restrict__ sel_cnt) {
  const int h = blockIdx.x;
  const int tid = threadIdx.x;
  const int lane = tid & 63;
  const int wid = tid >> 6;
  __shared__ u64 keys[S_LEN];
  __shared__ int waveTot[16];
  const int t0 = tid * 2;
  float c0 = 0.f, c1 = 0.f;
#pragma unroll
  for (int l = 0; l < LTAB; ++l) {
    const int2 kh = *reinterpret_cast<const int2*>(&k_hard[(size_t)(h * LTAB + l) * S_LEN + t0]);
    c0 += q_probs[(h * LTAB + l) * RBKT + kh.x];
    c1 += q_probs[(h * LTAB + l) * RBKT + kh.y];
  }
  const int2 al = *reinterpret_cast<const int2*>(&allowed[h * S_LEN + t0]);
  const float2 vn = *reinterpret_cast<const float2*>(&v_norm[h * S_LEN + t0]);
  const float s0 = al.x ? c0 * vn.x : -INFINITY;
  const float s1 = al.y ? c1 * vn.y : -INFINITY;
  auto mkkey = [](float s, int t) -> u64 {
    unsigned m = __float_as_uint(s);
    m = (m & 0x80000000u) ? ~m : (m | 0x80000000u);
    return ((u64)m << 11) | (u64)(S_LEN - 1 - t);
  };
  const u64 k0 = mkkey(s0, t0);
  const u64 k1 = mkkey(s1, t0 + 1);
  keys[t0] = k0;
  keys[t0 + 1] = k1;
  __syncthreads();
  int r0 = 0, r1 = 0;
#pragma unroll 8
  for (int u = 0; u < S_LEN; u += 2) {
    const u64x2 kv = *reinterpret_cast<const u64x2*>(&keys[u]);
    r0 += (kv.x > k0) + (kv.y > k0);
    r1 += (kv.x > k1) + (kv.y > k1);
  }
  const int Mv = min(Mp[0], S_LEN);
  int sv = sinkp[0];
  sv = sv < 0 ? 0 : (sv > S_LEN ? S_LEN : sv);
  int wv = winp[0];
  wv = wv < 0 ? 0 : (wv > S_LEN ? S_LEN : wv);
  int wstart = S_LEN - wv;
  if (wstart < sv) wstart = sv;
  bool sel0 = r0 < Mv, sel1 = r1 < Mv;
  if (t0 < sv) sel0 = true;
  if (t0 + 1 < sv) sel1 = true;
  if (wv > 0) {
    if (t0 >= wstart) sel0 = true;
    if (t0 + 1 >= wstart) sel1 = true;
  }
  if (sv == 0 && wv == 0) {
    if (t0 == S_LEN - 1) sel0 = true;
    if (t0 + 1 == S_LEN - 1) sel1 = true;
  }
  sel0 = sel0 && (al.x != 0);
  sel1 = sel1 && (al.y != 0);
  const int cnt = (sel0 ? 1 : 0) + (sel1 ? 1 : 0);
  int inc = cnt;
#pragma unroll
  for (int off = 1; off < 64; off <<= 1) {
    int n = __shfl_up(inc, off);
    if (lane >= off) inc += n;
  }
  if (lane == 63) waveTot[wid] = inc;
  __syncthreads();
  int wbase = 0;
  for (int w = 0; w < wid; ++w) wbase += waveTot[w];
  int pos = wbase + inc - cnt;
  if (tid == 0) {
    int tot = 0;
#pragma unroll
    for (int w = 0; w < 16; ++w) tot += waveTot[w];
    sel_cnt[h] = tot;
  }
  if (sel0) sel_idx[h * S_LEN + pos++] = t0;
  if (sel1) sel_idx[h * S_LEN + pos] = t0 + 1;
}

// ---------------- flash attention over compacted key list ----------------
// R3-proven V path (Vt transposed staging + vector ds_read); safe upgrades only:
// ones-broadcast MFMA row-sum (layout-independent) + lane-local defer-max gate.
__global__ __launch_bounds__(256) void attn_kernel(const __hip_bfloat16* __restrict__ Qro,
                                                   const __hip_bfloat16* __restrict__ Kro,
                                                   const __hip_bfloat16* __restrict__ Vpk,
                                                   const int* __restrict__ sel_idx,
                                                   const int* __restrict__ sel_cnt,
                                                   __hip_bfloat16* __restrict__ ctx) {
  constexpr int BKV = 32;
  const int h = blockIdx.y;
  const int q0 = blockIdx.x * 64;
  const int tid = threadIdx.x, wid = tid >> 6, lane = tid & 63;
  const int kv = h >> 2;
  __shared__ __hip_bfloat16 Ks[BKV][DH + 8];
  __shared__ __hip_bfloat16 Vt[DH][BKV + 8];
  __shared__ __hip_bfloat16 Ps[4][16][BKV + 8];
  __shared__ int tIdx[BKV];
  const int qbase = q0 + wid * 16;
  const float scaling = 0.08838834764831845f;  // 128^-0.5 (pre-applied to Q)
  s16x8 qf[4];
  {
    const __hip_bfloat16* qp =
        Qro + (size_t)(qbase + (lane & 15)) * (NH * DH) + h * DH + (lane >> 4) * 8;
#pragma unroll
    for (int kt = 0; kt < 4; ++kt) {
      s16x8 q = *reinterpret_cast<const s16x8*>(qp + kt * 32);
#pragma unroll
      for (int j = 0; j < 8; ++j) q[j] = bf16s(s2f(q[j]) * scaling);
      qf[kt] = q;
    }
  }
  s16x8 ones;
#pragma unroll
  for (int j = 0; j < 8; ++j) ones[j] = (short)0x3F80;  // bf16 1.0
  float mr[4], lr[4];
#pragma unroll
  for (int r = 0; r < 4; ++r) {
    mr[r] = -3.0e38f;
    lr[r] = 0.f;
  }
  f32x4 o[8] = {};
  const int cnt = sel_cnt[h];
  const int qmax = q0 + 63;
  for (int j0 = 0; j0 < cnt; j0 += BKV) {
    if (sel_idx[h * S_LEN + j0] > qmax) break;  // ascending list: rest is masked
    const int nk = min(BKV, cnt - j0);
    __syncthreads();
    if (tid < BKV) tIdx[tid] = (tid < nk) ? sel_idx[h * S_LEN + j0 + tid] : 0x7fffffff;
#pragma unroll
    for (int c = 0; c < 2; ++c) {
      const int ch = tid + c * 256;
      const int row = ch >> 4, c8 = ch & 15;
      if (row < nk) {
        const int t = sel_idx[h * S_LEN + j0 + row];
        *reinterpret_cast<s16x8*>(&Ks[row][c8 * 8]) = *reinterpret_cast<const s16x8*>(
            Kro + (size_t)t * (NKV * DH) + kv * DH + c8 * 8);
      }
    }
    {
      const int j = tid >> 3;          // key slot 0..31
      const int dp = (tid & 7) * 16;   // dim chunk
      if (j < nk) {
        const int t = sel_idx[h * S_LEN + j0 + j];
        const __hip_bfloat16* vp = Vpk + (size_t)t * NQKV + kv * DH + dp;
        s16x8 a = *reinterpret_cast<const s16x8*>(vp);
        s16x8 b = *reinterpret_cast<const s16x8*>(vp + 8);
#pragma unroll
        for (int i = 0; i < 8; ++i) reinterpret_cast<short&>(Vt[dp + i][j]) = a[i];
#pragma unroll
        for (int i = 0; i < 8; ++i) reinterpret_cast<short&>(Vt[dp + 8 + i][j]) = b[i];
      } else {
#pragma unroll
        for (int i = 0; i < 16; ++i) reinterpret_cast<short&>(Vt[dp + i][j]) = 0;
      }
    }
    __syncthreads();
    // QK^T : D[q][key], two 16-key column tiles
    f32x4 s0 = {0.f, 0.f, 0.f, 0.f}, s1 = {0.f, 0.f, 0.f, 0.f};
#pragma unroll
    for (int kt = 0; kt < 4; ++kt) {
      s16x8 k0 = *reinterpret_cast<const s16x8*>(&Ks[lane & 15][kt * 32 + (lane >> 4) * 8]);
      s16x8 k1 = *reinterpret_cast<const s16x8*>(&Ks[16 + (lane & 15)][kt * 32 + (lane >> 4) * 8]);
      s0 = __builtin_amdgcn_mfma_f32_16x16x32_bf16(qf[kt], k0, s0, 0, 0, 0);
      s1 = __builtin_amdgcn_mfma_f32_16x16x32_bf16(qf[kt], k1, s1, 0, 0, 0);
    }
    const int t0 = tIdx[lane & 15];
    const int t1 = tIdx[16 + (lane & 15)];
    float v0[4], v1[4];
    bool need = false;
#pragma unroll
    for (int r = 0; r < 4; ++r) {
      const int qs = qbase + ((lane >> 4) << 2) + r;
      v0[r] = (t0 <= qs) ? s0[r] : -1.0e9f;
      v1[r] = (t1 <= qs) ? s1[r] : -1.0e9f;
      need = need || (fmaxf(v0[r], v1[r]) > mr[r] + 8.f);
    }
    if (__any(need)) {  // rare path: true row-max via shfl, then rescale
#pragma unroll
      for (int r = 0; r < 4; ++r) {
        float m = fmaxf(v0[r], v1[r]);
#pragma unroll
        for (int off = 1; off < 16; off <<= 1) m = fmaxf(m, __shfl_xor(m, off));
        const float mn = fmaxf(mr[r], m);
        const float scl = __expf(mr[r] - mn);
        lr[r] *= scl;
#pragma unroll
        for (int nt = 0; nt < 8; ++nt) o[nt][r] *= scl;
        mr[r] = mn;
      }
    }
#pragma unroll
    for (int r = 0; r < 4; ++r) {
      const float p0 = __expf(v0[r] - mr[r]);
      const float p1 = __expf(v1[r] - mr[r]);
      Ps[wid][((lane >> 4) << 2) + r][lane & 15] = __float2bfloat16(p0);
      Ps[wid][((lane >> 4) << 2) + r][16 + (lane & 15)] = __float2bfloat16(p1);
    }
    const s16x8 pf = *reinterpret_cast<const s16x8*>(&Ps[wid][lane & 15][(lane >> 4) * 8]);
    {  // row-sum via ones-broadcast MFMA: D[q][*] = sum_k P[q][k] (layout-independent)
      f32x4 zero = {0.f, 0.f, 0.f, 0.f};
      f32x4 psum = __builtin_amdgcn_mfma_f32_16x16x32_bf16(pf, ones, zero, 0, 0, 0);
#pragma unroll
      for (int r = 0; r < 4; ++r) lr[r] += psum[r];
    }
#pragma unroll
    for (int nt = 0; nt < 8; ++nt) {
      const s16x8 vf =
          *reinterpret_cast<const s16x8*>(&Vt[nt * 16 + (lane & 15)][(lane >> 4) * 8]);
      o[nt] = __builtin_amdgcn_mfma_f32_16x16x32_bf16(pf, vf, o[nt], 0, 0, 0);
    }
  }
#pragma unroll
  for (int nt = 0; nt < 8; ++nt)
#pragma unroll
    for (int r = 0; r < 4; ++r) {
      const int qs = qbase + ((lane >> 4) << 2) + r;
      const int d = nt * 16 + (lane & 15);
      ctx[(size_t)qs * (NH * DH) + h * DH + d] = __float2bfloat16(o[nt][r] / lr[r]);
    }
}

}  // namespace

extern "C" void kernel_launch(void* const* d_in, const int* in_sizes, int n_in,
                              void* d_out, int out_size, void* d_ws, size_t ws_size,
                              hipStream_t stream) {
  const float* hidden = (const float*)d_in[0];
  const float* cosb = (const float*)d_in[1];
  const float* sinb = (const float*)d_in[2];
  const float* q_probs = (const float*)d_in[3];
  const float* v_norm = (const float*)d_in[4];
  const int* allowed = (const int*)d_in[5];
  const int* k_hard = (const int*)d_in[6];
  const float* Wq = (const float*)d_in[7];
  const float* Wk = (const float*)d_in[8];
  const float* Wv = (const float*)d_in[9];
  const float* Wo = (const float*)d_in[10];
  const int* sinkp = (const int*)d_in[11];
  const int* winp = (const int*)d_in[12];
  const int* Mp = (const int*)d_in[13];

  char* ws = (char*)d_ws;
  size_t off = 0;
  auto alloc = [&](size_t bytes) -> char* {
    char* p = ws + off;
    off += (bytes + 255) & ~(size_t)255;
    return p;
  };
  __hip_bfloat16* hbf = (__hip_bfloat16*)alloc((size_t)S_LEN * DM * 2);
  __hip_bfloat16* WqkvT = (__hip_bfloat16*)alloc((size_t)NQKV * DM * 2);  // packed [6144][4096]
  __hip_bfloat16* WoT = (__hip_bfloat16*)alloc((size_t)DM * DM * 2);
  __hip_bfloat16* QKV = (__hip_bfloat16*)alloc((size_t)S_LEN * NQKV * 2);
  __hip_bfloat16* Qro = (__hip_bfloat16*)alloc((size_t)S_LEN * NH * DH * 2);
  __hip_bfloat16* Kro = (__hip_bfloat16*)alloc((size_t)S_LEN * NKV * DH * 2);
  __hip_bfloat16* ctx = (__hip_bfloat16*)alloc((size_t)S_LEN * NH * DH * 2);
  int* sel_idx = (int*)alloc((size_t)NH * S_LEN * 4);
  int* sel_cnt = (int*)alloc((size_t)NH * 4);
  if (off > ws_size) return;

  {
    const int n4 = S_LEN * DM / 4;
    cvt_f32_bf16<<<(n4 + 255) / 256, 256, 0, stream>>>(hidden, hbf, n4);
  }
  transpose_cvt64<<<dim3(DM / 64, DM / 64), 256, 0, stream>>>(Wq, WqkvT, DM, DM);
  transpose_cvt64<<<dim3((NKV * DH) / 64, DM / 64), 256, 0, stream>>>(
      Wk, WqkvT + (size_t)KOFF * DM, DM, NKV * DH);
  transpose_cvt64<<<dim3((NKV * DH) / 64, DM / 64), 256, 0, stream>>>(
      Wv, WqkvT + (size_t)VOFF * DM, DM, NKV * DH);
  transpose_cvt64<<<dim3(DM / 64, DM / 64), 256, 0, stream>>>(Wo, WoT, DM, DM);

  gemm_bt<false><<<dim3(NQKV / 128, S_LEN / 128), 256, 0, stream>>>(
      hbf, WqkvT, (void*)QKV, NQKV, DM);

  rope_kernel<<<S_LEN, 256, 0, stream>>>(QKV, cosb, sinb, Qro, Kro);

  select_kernel<<<NH, 1024, 0, stream>>>(q_probs, v_norm, allowed, k_hard, sinkp, winp, Mp,
                                         sel_idx, sel_cnt);

  attn_kernel<<<dim3(S_LEN / 64, NH), 256, 0, stream>>>(Qro, Kro, QKV + VOFF, sel_idx,
                                                        sel_cnt, ctx);

  gemm_bt<true><<<dim3(DM / 128, S_LEN / 128), 256, 0, stream>>>(ctx, WoT, d_out, DM, DM);
}

// Round 6
// 411.897 us; speedup vs baseline: 3.0003x; 1.0262x over previous
//
#include <hip/hip_runtime.h>
#include <hip/hip_bf16.h>
#include <cstdint>
#include <cstddef>

namespace {

constexpr int S_LEN = 2048;
constexpr int DM    = 4096;
constexpr int NH    = 32;
constexpr int NKV   = 8;
constexpr int DH    = 128;
constexpr int LTAB  = 20;
constexpr int RBKT  = 128;
constexpr int NQKV  = NH * DH + 2 * NKV * DH;  // 6144 packed Q|K|V cols
constexpr int KOFF  = NH * DH;                 // 4096
constexpr int VOFF  = NH * DH + NKV * DH;      // 5120

typedef short s16x8 __attribute__((ext_vector_type(8)));
typedef float f32x4 __attribute__((ext_vector_type(4)));
typedef unsigned long long u64;
struct u64x2 { u64 x, y; };

__device__ inline short bf16s(float f) {
  __hip_bfloat16 b = __float2bfloat16(f);
  return (short)*reinterpret_cast<unsigned short*>(&b);
}
__device__ inline float s2f(short s) {
  unsigned short u = (unsigned short)s;
  return __bfloat162float(*reinterpret_cast<__hip_bfloat16*>(&u));
}

// ---------------- fp32 -> bf16 (flat) ----------------
__global__ __launch_bounds__(256) void cvt_f32_bf16(const float* __restrict__ in,
                                                    __hip_bfloat16* __restrict__ out,
                                                    int n4) {
  int i = blockIdx.x * blockDim.x + threadIdx.x;
  if (i >= n4) return;
  float4 v = reinterpret_cast<const float4*>(in)[i];
  ushort4 o;
  o.x = (unsigned short)bf16s(v.x);
  o.y = (unsigned short)bf16s(v.y);
  o.z = (unsigned short)bf16s(v.z);
  o.w = (unsigned short)bf16s(v.w);
  reinterpret_cast<ushort4*>(out)[i] = o;
}

// ------- transpose + convert: W[K][N] f32 -> Wt[N][K] bf16, 64x64 tiles, vectorized -------
__global__ __launch_bounds__(256) void transpose_cvt64(const float* __restrict__ W,
                                                       __hip_bfloat16* __restrict__ Wt,
                                                       int K, int N) {
  __shared__ float tile[64][65];
  const int kb = blockIdx.y * 64, nb = blockIdx.x * 64;
  const int tid = threadIdx.x;
  const int r0 = tid >> 4, c4 = (tid & 15) * 4;
#pragma unroll
  for (int it = 0; it < 4; ++it) {
    const int r = r0 + it * 16;
    float4 v = *reinterpret_cast<const float4*>(&W[(size_t)(kb + r) * N + nb + c4]);
    tile[r][c4] = v.x;
    tile[r][c4 + 1] = v.y;
    tile[r][c4 + 2] = v.z;
    tile[r][c4 + 3] = v.w;
  }
  __syncthreads();
  const int n0 = tid >> 4, k4 = (tid & 15) * 4;
#pragma unroll
  for (int it = 0; it < 4; ++it) {
    const int n = n0 + it * 16;
    ushort4 o;
    o.x = (unsigned short)bf16s(tile[k4][n]);
    o.y = (unsigned short)bf16s(tile[k4 + 1][n]);
    o.z = (unsigned short)bf16s(tile[k4 + 2][n]);
    o.w = (unsigned short)bf16s(tile[k4 + 3][n]);
    *reinterpret_cast<ushort4*>(&Wt[(size_t)(nb + n) * K + kb + k4]) = o;
  }
}

// ---------------- bf16 GEMM: C[M][N] = A[M][K] * Bt[N][K]^T ----------------
// 128x128 tile, BK=64, 4 waves (2x2), mfma 16x16x32, swizzled global_load_lds staging.
// (XCD blockIdx swizzle removed: R5 measured FETCH_SIZE 112->295 MB regression.)
template <bool OUT_F32>
__global__ __launch_bounds__(256) void gemm_bt(const __hip_bfloat16* __restrict__ A,
                                               const __hip_bfloat16* __restrict__ Bt,
                                               void* __restrict__ Cout,
                                               int N, int K) {
  __shared__ __hip_bfloat16 As[128 * 64];
  __shared__ __hip_bfloat16 Bs[128 * 64];
  const int tid = threadIdx.x;
  const int wid = tid >> 6;
  const int lane = tid & 63;
  const int bm = blockIdx.y, bn = blockIdx.x;
  const int wr = wid >> 1, wc = wid & 1;
  f32x4 acc[4][4] = {};
  const __hip_bfloat16* Abase = A + (size_t)bm * 128 * K;
  const __hip_bfloat16* Bbase = Bt + (size_t)bn * 128 * K;
  for (int kt = 0; kt < K; kt += 64) {
    __syncthreads();
#pragma unroll
    for (int j = 0; j < 4; ++j) {
      const int pb = j * 4096 + wid * 1024;  // wave-uniform LDS byte base
      const int p = pb + lane * 16;          // this lane's linear dest byte
      const int row = p >> 7;                // 0..127 (row = 128B of bf16, BK=64)
      const int slot = ((p >> 4) & 7) ^ (row & 7);  // inverse-swizzled source slot
      const int goff = row * K + kt + slot * 8;
      __builtin_amdgcn_global_load_lds(
          (const __attribute__((address_space(1))) void*)(Abase + goff),
          (__attribute__((address_space(3))) void*)(As + (pb >> 1)), 16, 0, 0);
      __builtin_amdgcn_global_load_lds(
          (const __attribute__((address_space(1))) void*)(Bbase + goff),
          (__attribute__((address_space(3))) void*)(Bs + (pb >> 1)), 16, 0, 0);
    }
    __syncthreads();
#pragma unroll
    for (int kk = 0; kk < 2; ++kk) {
      s16x8 af[4], bf[4];
#pragma unroll
      for (int i = 0; i < 4; ++i) {
        const int ra = wr * 64 + i * 16 + (lane & 15);
        const int sa = (kk * 4 + (lane >> 4)) ^ (ra & 7);
        af[i] = *reinterpret_cast<const s16x8*>(As + ra * 64 + sa * 8);
        const int rb = wc * 64 + i * 16 + (lane & 15);
        const int sb = (kk * 4 + (lane >> 4)) ^ (rb & 7);
        bf[i] = *reinterpret_cast<const s16x8*>(Bs + rb * 64 + sb * 8);
      }
#pragma unroll
      for (int i = 0; i < 4; ++i)
#pragma unroll
        for (int jn = 0; jn < 4; ++jn)
          acc[i][jn] = __builtin_amdgcn_mfma_f32_16x16x32_bf16(af[i], bf[jn], acc[i][jn], 0, 0, 0);
    }
  }
  const int rg = (lane >> 4) * 4;
  const int cg = lane & 15;
#pragma unroll
  for (int i = 0; i < 4; ++i)
#pragma unroll
    for (int jn = 0; jn < 4; ++jn)
#pragma unroll
      for (int r = 0; r < 4; ++r) {
        const int rr = bm * 128 + wr * 64 + i * 16 + rg + r;
        const int cc = bn * 128 + wc * 64 + jn * 16 + cg;
        if (OUT_F32)
          reinterpret_cast<float*>(Cout)[(size_t)rr * N + cc] = acc[i][jn][r];
        else
          reinterpret_cast<__hip_bfloat16*>(Cout)[(size_t)rr * N + cc] =
              __float2bfloat16(acc[i][jn][r]);
      }
}

// ---------------- RoPE on packed QKV -> Qro [S][4096], Kro [S][1024] ----------------
__global__ __launch_bounds__(256) void rope_kernel(const __hip_bfloat16* __restrict__ QKV,
                                                   const float* __restrict__ cosb,
                                                   const float* __restrict__ sinb,
                                                   __hip_bfloat16* __restrict__ Qro,
                                                   __hip_bfloat16* __restrict__ Kro) {
  const int s = blockIdx.x;
  const int tid = threadIdx.x;
  const float* cs = cosb + s * DH;
  const float* sn = sinb + s * DH;
  const __hip_bfloat16* row = QKV + (size_t)s * NQKV;
  for (int ch = tid; ch < 512 + 128; ch += 256) {
    const bool isQ = ch < 512;
    const int idx8 = (isQ ? ch : ch - 512) * 8;
    const int d8 = idx8 & (DH - 1);
    const int hb = idx8 - d8;
    const __hip_bfloat16* src = isQ ? row : row + KOFF;
    s16x8 v = *reinterpret_cast<const s16x8*>(src + idx8);
    s16x8 p = *reinterpret_cast<const s16x8*>(src + hb + (d8 ^ 64));
    const float sgn = (d8 < 64) ? -1.f : 1.f;
    s16x8 outv;
#pragma unroll
    for (int j = 0; j < 8; ++j) {
      const float r = s2f(v[j]) * cs[d8 + j] + sgn * s2f(p[j]) * sn[d8 + j];
      outv[j] = bf16s(r);
    }
    if (isQ)
      *reinterpret_cast<s16x8*>(Qro + (size_t)s * (NH * DH) + idx8) = outv;
    else
      *reinterpret_cast<s16x8*>(Kro + (size_t)s * (NKV * DH) + idx8) = outv;
  }
}

// ---------------- exact top-M key selection + sink/window, compacted ascending -------
__global__ __launch_bounds__(1024) void select_kernel(const float* __restrict__ q_probs,
                                                      const float* __restrict__ v_norm,
                                                      const int* __restrict__ allowed,
                                                      const int* __restrict__ k_hard,
                                                      const int* __restrict__ sinkp,
                                                      const int* __restrict__ winp,
                                                      const int* __restrict__ Mp,
                                                      int* __restrict__ sel_idx,
                                                      int* __restrict__ sel_cnt) {
  const int h = blockIdx.x;
  const int tid = threadIdx.x;
  const int lane = tid & 63;
  const int wid = tid >> 6;
  __shared__ u64 keys[S_LEN];
  __shared__ int waveTot[16];
  const int t0 = tid * 2;
  float c0 = 0.f, c1 = 0.f;
#pragma unroll
  for (int l = 0; l < LTAB; ++l) {
    const int2 kh = *reinterpret_cast<const int2*>(&k_hard[(size_t)(h * LTAB + l) * S_LEN + t0]);
    c0 += q_probs[(h * LTAB + l) * RBKT + kh.x];
    c1 += q_probs[(h * LTAB + l) * RBKT + kh.y];
  }
  const int2 al = *reinterpret_cast<const int2*>(&allowed[h * S_LEN + t0]);
  const float2 vn = *reinterpret_cast<const float2*>(&v_norm[h * S_LEN + t0]);
  const float s0 = al.x ? c0 * vn.x : -INFINITY;
  const float s1 = al.y ? c1 * vn.y : -INFINITY;
  auto mkkey = [](float s, int t) -> u64 {
    unsigned m = __float_as_uint(s);
    m = (m & 0x80000000u) ? ~m : (m | 0x80000000u);
    return ((u64)m << 11) | (u64)(S_LEN - 1 - t);
  };
  const u64 k0 = mkkey(s0, t0);
  const u64 k1 = mkkey(s1, t0 + 1);
  keys[t0] = k0;
  keys[t0 + 1] = k1;
  __syncthreads();
  int r0 = 0, r1 = 0;
#pragma unroll 8
  for (int u = 0; u < S_LEN; u += 2) {
    const u64x2 kv = *reinterpret_cast<const u64x2*>(&keys[u]);
    r0 += (kv.x > k0) + (kv.y > k0);
    r1 += (kv.x > k1) + (kv.y > k1);
  }
  const int Mv = min(Mp[0], S_LEN);
  int sv = sinkp[0];
  sv = sv < 0 ? 0 : (sv > S_LEN ? S_LEN : sv);
  int wv = winp[0];
  wv = wv < 0 ? 0 : (wv > S_LEN ? S_LEN : wv);
  int wstart = S_LEN - wv;
  if (wstart < sv) wstart = sv;
  bool sel0 = r0 < Mv, sel1 = r1 < Mv;
  if (t0 < sv) sel0 = true;
  if (t0 + 1 < sv) sel1 = true;
  if (wv > 0) {
    if (t0 >= wstart) sel0 = true;
    if (t0 + 1 >= wstart) sel1 = true;
  }
  if (sv == 0 && wv == 0) {
    if (t0 == S_LEN - 1) sel0 = true;
    if (t0 + 1 == S_LEN - 1) sel1 = true;
  }
  sel0 = sel0 && (al.x != 0);
  sel1 = sel1 && (al.y != 0);
  const int cnt = (sel0 ? 1 : 0) + (sel1 ? 1 : 0);
  int inc = cnt;
#pragma unroll
  for (int off = 1; off < 64; off <<= 1) {
    int n = __shfl_up(inc, off);
    if (lane >= off) inc += n;
  }
  if (lane == 63) waveTot[wid] = inc;
  __syncthreads();
  int wbase = 0;
  for (int w = 0; w < wid; ++w) wbase += waveTot[w];
  int pos = wbase + inc - cnt;
  if (tid == 0) {
    int tot = 0;
#pragma unroll
    for (int w = 0; w < 16; ++w) tot += waveTot[w];
    sel_cnt[h] = tot;
  }
  if (sel0) sel_idx[h * S_LEN + pos++] = t0;
  if (sel1) sel_idx[h * S_LEN + pos] = t0 + 1;
}

// ---------------- flash attention over compacted key list ----------------
// V staged transposed with column-group XOR swizzle: write side 8-way -> free,
// read side unchanged bank pattern (d>>4 uniform across read lanes).
__global__ __launch_bounds__(256) void attn_kernel(const __hip_bfloat16* __restrict__ Qro,
                                                   const __hip_bfloat16* __restrict__ Kro,
                                                   const __hip_bfloat16* __restrict__ Vpk,
                                                   const int* __restrict__ sel_idx,
                                                   const int* __restrict__ sel_cnt,
                                                   __hip_bfloat16* __restrict__ ctx) {
  constexpr int BKV = 32;
  const int h = blockIdx.y;
  const int q0 = blockIdx.x * 64;
  const int tid = threadIdx.x, wid = tid >> 6, lane = tid & 63;
  const int kv = h >> 2;
  __shared__ __hip_bfloat16 Ks[BKV][DH + 8];
  __shared__ __hip_bfloat16 Vt[DH][BKV + 8];
  __shared__ __hip_bfloat16 Ps[4][16][BKV + 8];
  __shared__ int tIdx[BKV];
  const int qbase = q0 + wid * 16;
  const float scaling = 0.08838834764831845f;  // 128^-0.5 (pre-applied to Q)
  s16x8 qf[4];
  {
    const __hip_bfloat16* qp =
        Qro + (size_t)(qbase + (lane & 15)) * (NH * DH) + h * DH + (lane >> 4) * 8;
#pragma unroll
    for (int kt = 0; kt < 4; ++kt) {
      s16x8 q = *reinterpret_cast<const s16x8*>(qp + kt * 32);
#pragma unroll
      for (int j = 0; j < 8; ++j) q[j] = bf16s(s2f(q[j]) * scaling);
      qf[kt] = q;
    }
  }
  s16x8 ones;
#pragma unroll
  for (int j = 0; j < 8; ++j) ones[j] = (short)0x3F80;  // bf16 1.0
  float mr[4], lr[4];
#pragma unroll
  for (int r = 0; r < 4; ++r) {
    mr[r] = -3.0e38f;
    lr[r] = 0.f;
  }
  f32x4 o[8] = {};
  const int cnt = sel_cnt[h];
  const int qmax = q0 + 63;
  for (int j0 = 0; j0 < cnt; j0 += BKV) {
    if (sel_idx[h * S_LEN + j0] > qmax) break;  // ascending list: rest is masked
    const int nk = min(BKV, cnt - j0);
    __syncthreads();
    if (tid < BKV) tIdx[tid] = (tid < nk) ? sel_idx[h * S_LEN + j0 + tid] : 0x7fffffff;
#pragma unroll
    for (int c = 0; c < 2; ++c) {
      const int ch = tid + c * 256;
      const int row = ch >> 4, c8 = ch & 15;
      if (row < nk) {
        const int t = sel_idx[h * S_LEN + j0 + row];
        *reinterpret_cast<s16x8*>(&Ks[row][c8 * 8]) = *reinterpret_cast<const s16x8*>(
            Kro + (size_t)t * (NKV * DH) + kv * DH + c8 * 8);
      }
    }
    {
      const int j = tid >> 3;                       // key slot 0..31
      const int dp = (tid & 7) * 16;                // dim chunk base
      const int cc = j ^ (((dp >> 4) & 3) << 3);    // column-group XOR swizzle
      if (j < nk) {
        const int t = sel_idx[h * S_LEN + j0 + j];
        const __hip_bfloat16* vp = Vpk + (size_t)t * NQKV + kv * DH + dp;
        s16x8 a = *reinterpret_cast<const s16x8*>(vp);
        s16x8 b = *reinterpret_cast<const s16x8*>(vp + 8);
#pragma unroll
        for (int i = 0; i < 8; ++i) reinterpret_cast<short&>(Vt[dp + i][cc]) = a[i];
#pragma unroll
        for (int i = 0; i < 8; ++i) reinterpret_cast<short&>(Vt[dp + 8 + i][cc]) = b[i];
      } else {
#pragma unroll
        for (int i = 0; i < 16; ++i) reinterpret_cast<short&>(Vt[dp + i][cc]) = 0;
      }
    }
    __syncthreads();
    // QK^T : D[q][key], two 16-key column tiles
    f32x4 s0 = {0.f, 0.f, 0.f, 0.f}, s1 = {0.f, 0.f, 0.f, 0.f};
#pragma unroll
    for (int kt = 0; kt < 4; ++kt) {
      s16x8 k0 = *reinterpret_cast<const s16x8*>(&Ks[lane & 15][kt * 32 + (lane >> 4) * 8]);
      s16x8 k1 = *reinterpret_cast<const s16x8*>(&Ks[16 + (lane & 15)][kt * 32 + (lane >> 4) * 8]);
      s0 = __builtin_amdgcn_mfma_f32_16x16x32_bf16(qf[kt], k0, s0, 0, 0, 0);
      s1 = __builtin_amdgcn_mfma_f32_16x16x32_bf16(qf[kt], k1, s1, 0, 0, 0);
    }
    const int t0 = tIdx[lane & 15];
    const int t1 = tIdx[16 + (lane & 15)];
    float v0[4], v1[4];
    bool need = false;
#pragma unroll
    for (int r = 0; r < 4; ++r) {
      const int qs = qbase + ((lane >> 4) << 2) + r;
      v0[r] = (t0 <= qs) ? s0[r] : -1.0e9f;
      v1[r] = (t1 <= qs) ? s1[r] : -1.0e9f;
      need = need || (fmaxf(v0[r], v1[r]) > mr[r] + 8.f);
    }
    if (__any(need)) {  // rare path: true row-max via shfl, then rescale
#pragma unroll
      for (int r = 0; r < 4; ++r) {
        float m = fmaxf(v0[r], v1[r]);
#pragma unroll
        for (int off = 1; off < 16; off <<= 1) m = fmaxf(m, __shfl_xor(m, off));
        const float mn = fmaxf(mr[r], m);
        const float scl = __expf(mr[r] - mn);
        lr[r] *= scl;
#pragma unroll
        for (int nt = 0; nt < 8; ++nt) o[nt][r] *= scl;
        mr[r] = mn;
      }
    }
#pragma unroll
    for (int r = 0; r < 4; ++r) {
      const float p0 = __expf(v0[r] - mr[r]);
      const float p1 = __expf(v1[r] - mr[r]);
      Ps[wid][((lane >> 4) << 2) + r][lane & 15] = __float2bfloat16(p0);
      Ps[wid][((lane >> 4) << 2) + r][16 + (lane & 15)] = __float2bfloat16(p1);
    }
    const s16x8 pf = *reinterpret_cast<const s16x8*>(&Ps[wid][lane & 15][(lane >> 4) * 8]);
    {  // row-sum via ones-broadcast MFMA: D[q][*] = sum_k P[q][k] (layout-independent)
      f32x4 zero = {0.f, 0.f, 0.f, 0.f};
      f32x4 psum = __builtin_amdgcn_mfma_f32_16x16x32_bf16(pf, ones, zero, 0, 0, 0);
#pragma unroll
      for (int r = 0; r < 4; ++r) lr[r] += psum[r];
    }
#pragma unroll
    for (int nt = 0; nt < 8; ++nt) {
      const s16x8 vf = *reinterpret_cast<const s16x8*>(
          &Vt[nt * 16 + (lane & 15)][(((lane >> 4) ^ nt) & 3) * 8]);
      o[nt] = __builtin_amdgcn_mfma_f32_16x16x32_bf16(pf, vf, o[nt], 0, 0, 0);
    }
  }
#pragma unroll
  for (int nt = 0; nt < 8; ++nt)
#pragma unroll
    for (int r = 0; r < 4; ++r) {
      const int qs = qbase + ((lane >> 4) << 2) + r;
      const int d = nt * 16 + (lane & 15);
      ctx[(size_t)qs * (NH * DH) + h * DH + d] = __float2bfloat16(o[nt][r] / lr[r]);
    }
}

}  // namespace

extern "C" void kernel_launch(void* const* d_in, const int* in_sizes, int n_in,
                              void* d_out, int out_size, void* d_ws, size_t ws_size,
                              hipStream_t stream) {
  const float* hidden = (const float*)d_in[0];
  const float* cosb = (const float*)d_in[1];
  const float* sinb = (const float*)d_in[2];
  const float* q_probs = (const float*)d_in[3];
  const float* v_norm = (const float*)d_in[4];
  const int* allowed = (const int*)d_in[5];
  const int* k_hard = (const int*)d_in[6];
  const float* Wq = (const float*)d_in[7];
  const float* Wk = (const float*)d_in[8];
  const float* Wv = (const float*)d_in[9];
  const float* Wo = (const float*)d_in[10];
  const int* sinkp = (const int*)d_in[11];
  const int* winp = (const int*)d_in[12];
  const int* Mp = (const int*)d_in[13];

  char* ws = (char*)d_ws;
  size_t off = 0;
  auto alloc = [&](size_t bytes) -> char* {
    char* p = ws + off;
    off += (bytes + 255) & ~(size_t)255;
    return p;
  };
  __hip_bfloat16* hbf = (__hip_bfloat16*)alloc((size_t)S_LEN * DM * 2);
  __hip_bfloat16* WqkvT = (__hip_bfloat16*)alloc((size_t)NQKV * DM * 2);  // packed [6144][4096]
  __hip_bfloat16* WoT = (__hip_bfloat16*)alloc((size_t)DM * DM * 2);
  __hip_bfloat16* QKV = (__hip_bfloat16*)alloc((size_t)S_LEN * NQKV * 2);
  __hip_bfloat16* Qro = (__hip_bfloat16*)alloc((size_t)S_LEN * NH * DH * 2);
  __hip_bfloat16* Kro = (__hip_bfloat16*)alloc((size_t)S_LEN * NKV * DH * 2);
  __hip_bfloat16* ctx = (__hip_bfloat16*)alloc((size_t)S_LEN * NH * DH * 2);
  int* sel_idx = (int*)alloc((size_t)NH * S_LEN * 4);
  int* sel_cnt = (int*)alloc((size_t)NH * 4);
  if (off > ws_size) return;

  {
    const int n4 = S_LEN * DM / 4;
    cvt_f32_bf16<<<(n4 + 255) / 256, 256, 0, stream>>>(hidden, hbf, n4);
  }
  transpose_cvt64<<<dim3(DM / 64, DM / 64), 256, 0, stream>>>(Wq, WqkvT, DM, DM);
  transpose_cvt64<<<dim3((NKV * DH) / 64, DM / 64), 256, 0, stream>>>(
      Wk, WqkvT + (size_t)KOFF * DM, DM, NKV * DH);
  transpose_cvt64<<<dim3((NKV * DH) / 64, DM / 64), 256, 0, stream>>>(
      Wv, WqkvT + (size_t)VOFF * DM, DM, NKV * DH);
  transpose_cvt64<<<dim3(DM / 64, DM / 64), 256, 0, stream>>>(Wo, WoT, DM, DM);

  gemm_bt<false><<<dim3(NQKV / 128, S_LEN / 128), 256, 0, stream>>>(
      hbf, WqkvT, (void*)QKV, NQKV, DM);

  rope_kernel<<<S_LEN, 256, 0, stream>>>(QKV, cosb, sinb, Qro, Kro);

  select_kernel<<<NH, 1024, 0, stream>>>(q_probs, v_norm, allowed, k_hard, sinkp, winp, Mp,
                                         sel_idx, sel_cnt);

  attn_kernel<<<dim3(S_LEN / 64, NH), 256, 0, stream>>>(Qro, Kro, QKV + VOFF, sel_idx,
                                                        sel_cnt, ctx);

  gemm_bt<true><<<dim3(DM / 128, S_LEN / 128), 256, 0, stream>>>(ctx, WoT, d_out, DM, DM);
}

// Round 7
// 387.706 us; speedup vs baseline: 3.1875x; 1.0624x over previous
//
#include <hip/hip_runtime.h>
#include <hip/hip_bf16.h>
#include <cstdint>
#include <cstddef>

namespace {

constexpr int S_LEN = 2048;
constexpr int DM    = 4096;
constexpr int NH    = 32;
constexpr int NKV   = 8;
constexpr int DH    = 128;
constexpr int LTAB  = 20;
constexpr int RBKT  = 128;
constexpr int NQKV  = NH * DH + 2 * NKV * DH;  // 6144 packed Q|K|V cols
constexpr int KOFF  = NH * DH;                 // 4096
constexpr int VOFF  = NH * DH + NKV * DH;      // 5120

typedef short s16x8 __attribute__((ext_vector_type(8)));
typedef float f32x4 __attribute__((ext_vector_type(4)));
typedef unsigned long long u64;
struct u64x2 { u64 x, y; };

__device__ inline short bf16s(float f) {
  __hip_bfloat16 b = __float2bfloat16(f);
  return (short)*reinterpret_cast<unsigned short*>(&b);
}
__device__ inline float s2f(short s) {
  unsigned short u = (unsigned short)s;
  return __bfloat162float(*reinterpret_cast<__hip_bfloat16*>(&u));
}

// ------- fused prep: cvt(hidden->bf16) + 4 weight transpose/converts, 1 dispatch -------
// regions: [0,2048) cvt; [2048,6144) Wq; [6144,7168) Wk; [7168,8192) Wv; [8192,12288) Wo
__global__ __launch_bounds__(256) void prep_kernel(const float* __restrict__ hidden,
                                                   const float* __restrict__ Wq,
                                                   const float* __restrict__ Wk,
                                                   const float* __restrict__ Wv,
                                                   const float* __restrict__ Wo,
                                                   __hip_bfloat16* __restrict__ hbf,
                                                   __hip_bfloat16* __restrict__ WqkvT,
                                                   __hip_bfloat16* __restrict__ WoT) {
  __shared__ float tile[64][65];
  const int b = blockIdx.x, tid = threadIdx.x;
  if (b < 2048) {  // cvt: 1024 float4 per block
    const size_t base = (size_t)b * 1024;
#pragma unroll
    for (int it = 0; it < 4; ++it) {
      const size_t i = base + it * 256 + tid;
      float4 v = reinterpret_cast<const float4*>(hidden)[i];
      ushort4 o;
      o.x = (unsigned short)bf16s(v.x);
      o.y = (unsigned short)bf16s(v.y);
      o.z = (unsigned short)bf16s(v.z);
      o.w = (unsigned short)bf16s(v.w);
      reinterpret_cast<ushort4*>(hbf)[i] = o;
    }
    return;
  }
  const float* W;
  __hip_bfloat16* Wt;
  int N, bx, by;
  int t = b - 2048;
  if (t < 4096) {
    W = Wq; Wt = WqkvT; N = DM; bx = t & 63; by = t >> 6;
  } else if (t < 5120) {
    t -= 4096; W = Wk; Wt = WqkvT + (size_t)KOFF * DM; N = NKV * DH; bx = t & 15; by = t >> 4;
  } else if (t < 6144) {
    t -= 5120; W = Wv; Wt = WqkvT + (size_t)VOFF * DM; N = NKV * DH; bx = t & 15; by = t >> 4;
  } else {
    t -= 6144; W = Wo; Wt = WoT; N = DM; bx = t & 63; by = t >> 6;
  }
  const int K = DM;
  const int kb = by * 64, nb = bx * 64;
  const int r0 = tid >> 4, c4 = (tid & 15) * 4;
#pragma unroll
  for (int it = 0; it < 4; ++it) {
    const int r = r0 + it * 16;
    float4 v = *reinterpret_cast<const float4*>(&W[(size_t)(kb + r) * N + nb + c4]);
    tile[r][c4] = v.x;
    tile[r][c4 + 1] = v.y;
    tile[r][c4 + 2] = v.z;
    tile[r][c4 + 3] = v.w;
  }
  __syncthreads();
  const int n0 = tid >> 4, k4 = (tid & 15) * 4;
#pragma unroll
  for (int it = 0; it < 4; ++it) {
    const int n = n0 + it * 16;
    ushort4 o;
    o.x = (unsigned short)bf16s(tile[k4][n]);
    o.y = (unsigned short)bf16s(tile[k4 + 1][n]);
    o.z = (unsigned short)bf16s(tile[k4 + 2][n]);
    o.w = (unsigned short)bf16s(tile[k4 + 3][n]);
    *reinterpret_cast<ushort4*>(&Wt[(size_t)(nb + n) * K + kb + k4]) = o;
  }
}

// ---------------- bf16 GEMM: C[M][N] = A[M][K] * Bt[N][K]^T ----------------
// 128x128 tile, BK=64, 4 waves (2x2), mfma 16x16x32, swizzled global_load_lds staging.
template <bool OUT_F32>
__global__ __launch_bounds__(256) void gemm_bt(const __hip_bfloat16* __restrict__ A,
                                               const __hip_bfloat16* __restrict__ Bt,
                                               void* __restrict__ Cout,
                                               int N, int K) {
  __shared__ __hip_bfloat16 As[128 * 64];
  __shared__ __hip_bfloat16 Bs[128 * 64];
  const int tid = threadIdx.x;
  const int wid = tid >> 6;
  const int lane = tid & 63;
  const int bm = blockIdx.y, bn = blockIdx.x;
  const int wr = wid >> 1, wc = wid & 1;
  f32x4 acc[4][4] = {};
  const __hip_bfloat16* Abase = A + (size_t)bm * 128 * K;
  const __hip_bfloat16* Bbase = Bt + (size_t)bn * 128 * K;
  for (int kt = 0; kt < K; kt += 64) {
    __syncthreads();
#pragma unroll
    for (int j = 0; j < 4; ++j) {
      const int pb = j * 4096 + wid * 1024;  // wave-uniform LDS byte base
      const int p = pb + lane * 16;          // this lane's linear dest byte
      const int row = p >> 7;                // 0..127 (row = 128B of bf16, BK=64)
      const int slot = ((p >> 4) & 7) ^ (row & 7);  // inverse-swizzled source slot
      const int goff = row * K + kt + slot * 8;
      __builtin_amdgcn_global_load_lds(
          (const __attribute__((address_space(1))) void*)(Abase + goff),
          (__attribute__((address_space(3))) void*)(As + (pb >> 1)), 16, 0, 0);
      __builtin_amdgcn_global_load_lds(
          (const __attribute__((address_space(1))) void*)(Bbase + goff),
          (__attribute__((address_space(3))) void*)(Bs + (pb >> 1)), 16, 0, 0);
    }
    __syncthreads();
#pragma unroll
    for (int kk = 0; kk < 2; ++kk) {
      s16x8 af[4], bf[4];
#pragma unroll
      for (int i = 0; i < 4; ++i) {
        const int ra = wr * 64 + i * 16 + (lane & 15);
        const int sa = (kk * 4 + (lane >> 4)) ^ (ra & 7);
        af[i] = *reinterpret_cast<const s16x8*>(As + ra * 64 + sa * 8);
        const int rb = wc * 64 + i * 16 + (lane & 15);
        const int sb = (kk * 4 + (lane >> 4)) ^ (rb & 7);
        bf[i] = *reinterpret_cast<const s16x8*>(Bs + rb * 64 + sb * 8);
      }
#pragma unroll
      for (int i = 0; i < 4; ++i)
#pragma unroll
        for (int jn = 0; jn < 4; ++jn)
          acc[i][jn] = __builtin_amdgcn_mfma_f32_16x16x32_bf16(af[i], bf[jn], acc[i][jn], 0, 0, 0);
    }
  }
  const int rg = (lane >> 4) * 4;
  const int cg = lane & 15;
#pragma unroll
  for (int i = 0; i < 4; ++i)
#pragma unroll
    for (int jn = 0; jn < 4; ++jn)
#pragma unroll
      for (int r = 0; r < 4; ++r) {
        const int rr = bm * 128 + wr * 64 + i * 16 + rg + r;
        const int cc = bn * 128 + wc * 64 + jn * 16 + cg;
        if (OUT_F32)
          reinterpret_cast<float*>(Cout)[(size_t)rr * N + cc] = acc[i][jn][r];
        else
          reinterpret_cast<__hip_bfloat16*>(Cout)[(size_t)rr * N + cc] =
              __float2bfloat16(acc[i][jn][r]);
      }
}

// ---------------- RoPE on packed QKV -> Qro [S][4096], Kro [S][1024] ----------------
__global__ __launch_bounds__(256) void rope_kernel(const __hip_bfloat16* __restrict__ QKV,
                                                   const float* __restrict__ cosb,
                                                   const float* __restrict__ sinb,
                                                   __hip_bfloat16* __restrict__ Qro,
                                                   __hip_bfloat16* __restrict__ Kro) {
  const int s = blockIdx.x;
  const int tid = threadIdx.x;
  const float* cs = cosb + s * DH;
  const float* sn = sinb + s * DH;
  const __hip_bfloat16* row = QKV + (size_t)s * NQKV;
  for (int ch = tid; ch < 512 + 128; ch += 256) {
    const bool isQ = ch < 512;
    const int idx8 = (isQ ? ch : ch - 512) * 8;
    const int d8 = idx8 & (DH - 1);
    const int hb = idx8 - d8;
    const __hip_bfloat16* src = isQ ? row : row + KOFF;
    s16x8 v = *reinterpret_cast<const s16x8*>(src + idx8);
    s16x8 p = *reinterpret_cast<const s16x8*>(src + hb + (d8 ^ 64));
    const float sgn = (d8 < 64) ? -1.f : 1.f;
    s16x8 outv;
#pragma unroll
    for (int j = 0; j < 8; ++j) {
      const float r = s2f(v[j]) * cs[d8 + j] + sgn * s2f(p[j]) * sn[d8 + j];
      outv[j] = bf16s(r);
    }
    if (isQ)
      *reinterpret_cast<s16x8*>(Qro + (size_t)s * (NH * DH) + idx8) = outv;
    else
      *reinterpret_cast<s16x8*>(Kro + (size_t)s * (NKV * DH) + idx8) = outv;
  }
}

// ---------------- exact top-M key selection + sink/window, compacted ascending -------
__global__ __launch_bounds__(1024) void select_kernel(const float* __restrict__ q_probs,
                                                      const float* __restrict__ v_norm,
                                                      const int* __restrict__ allowed,
                                                      const int* __restrict__ k_hard,
                                                      const int* __restrict__ sinkp,
                                                      const int* __restrict__ winp,
                                                      const int* __restrict__ Mp,
                                                      int* __restrict__ sel_idx,
                                                      int* __restrict__ sel_cnt) {
  const int h = blockIdx.x;
  const int tid = threadIdx.x;
  const int lane = tid & 63;
  const int wid = tid >> 6;
  __shared__ u64 keys[S_LEN];
  __shared__ int waveTot[16];
  const int t0 = tid * 2;
  float c0 = 0.f, c1 = 0.f;
#pragma unroll
  for (int l = 0; l < LTAB; ++l) {
    const int2 kh = *reinterpret_cast<const int2*>(&k_hard[(size_t)(h * LTAB + l) * S_LEN + t0]);
    c0 += q_probs[(h * LTAB + l) * RBKT + kh.x];
    c1 += q_probs[(h * LTAB + l) * RBKT + kh.y];
  }
  const int2 al = *reinterpret_cast<const int2*>(&allowed[h * S_LEN + t0]);
  const float2 vn = *reinterpret_cast<const float2*>(&v_norm[h * S_LEN + t0]);
  const float s0 = al.x ? c0 * vn.x : -INFINITY;
  const float s1 = al.y ? c1 * vn.y : -INFINITY;
  auto mkkey = [](float s, int t) -> u64 {
    unsigned m = __float_as_uint(s);
    m = (m & 0x80000000u) ? ~m : (m | 0x80000000u);
    return ((u64)m << 11) | (u64)(S_LEN - 1 - t);
  };
  const u64 k0 = mkkey(s0, t0);
  const u64 k1 = mkkey(s1, t0 + 1);
  keys[t0] = k0;
  keys[t0 + 1] = k1;
  __syncthreads();
  int r0 = 0, r1 = 0;
#pragma unroll 8
  for (int u = 0; u < S_LEN; u += 2) {
    const u64x2 kv = *reinterpret_cast<const u64x2*>(&keys[u]);
    r0 += (kv.x > k0) + (kv.y > k0);
    r1 += (kv.x > k1) + (kv.y > k1);
  }
  const int Mv = min(Mp[0], S_LEN);
  int sv = sinkp[0];
  sv = sv < 0 ? 0 : (sv > S_LEN ? S_LEN : sv);
  int wv = winp[0];
  wv = wv < 0 ? 0 : (wv > S_LEN ? S_LEN : wv);
  int wstart = S_LEN - wv;
  if (wstart < sv) wstart = sv;
  bool sel0 = r0 < Mv, sel1 = r1 < Mv;
  if (t0 < sv) sel0 = true;
  if (t0 + 1 < sv) sel1 = true;
  if (wv > 0) {
    if (t0 >= wstart) sel0 = true;
    if (t0 + 1 >= wstart) sel1 = true;
  }
  if (sv == 0 && wv == 0) {
    if (t0 == S_LEN - 1) sel0 = true;
    if (t0 + 1 == S_LEN - 1) sel1 = true;
  }
  sel0 = sel0 && (al.x != 0);
  sel1 = sel1 && (al.y != 0);
  const int cnt = (sel0 ? 1 : 0) + (sel1 ? 1 : 0);
  int inc = cnt;
#pragma unroll
  for (int off = 1; off < 64; off <<= 1) {
    int n = __shfl_up(inc, off);
    if (lane >= off) inc += n;
  }
  if (lane == 63) waveTot[wid] = inc;
  __syncthreads();
  int wbase = 0;
  for (int w = 0; w < wid; ++w) wbase += waveTot[w];
  int pos = wbase + inc - cnt;
  if (tid == 0) {
    int tot = 0;
#pragma unroll
    for (int w = 0; w < 16; ++w) tot += waveTot[w];
    sel_cnt[h] = tot;
  }
  if (sel0) sel_idx[h * S_LEN + pos++] = t0;
  if (sel1) sel_idx[h * S_LEN + pos] = t0 + 1;
}

// ---------------- flash attention, BKV=64 ----------------
// Vt col swizzle cc = key ^ (((d>>4)&7)<<3): write 2-way (free), read uniform.
__global__ __launch_bounds__(256) void attn_kernel(const __hip_bfloat16* __restrict__ Qro,
                                                   const __hip_bfloat16* __restrict__ Kro,
                                                   const __hip_bfloat16* __restrict__ Vpk,
                                                   const int* __restrict__ sel_idx,
                                                   const int* __restrict__ sel_cnt,
                                                   __hip_bfloat16* __restrict__ ctx) {
  constexpr int BKV = 64;
  const int h = blockIdx.y;
  const int q0 = blockIdx.x * 64;
  const int tid = threadIdx.x, wid = tid >> 6, lane = tid & 63;
  const int l15 = lane & 15, hi = lane >> 4;
  const int kv = h >> 2;
  __shared__ __hip_bfloat16 Ks[BKV][DH + 8];
  __shared__ __hip_bfloat16 Vt[DH][BKV + 8];
  __shared__ __hip_bfloat16 Ps[4][16][BKV + 8];
  __shared__ int tIdx[BKV];
  const int qbase = q0 + wid * 16;
  const float scaling = 0.08838834764831845f;  // 128^-0.5 (pre-applied to Q)
  s16x8 qf[4];
  {
    const __hip_bfloat16* qp =
        Qro + (size_t)(qbase + l15) * (NH * DH) + h * DH + hi * 8;
#pragma unroll
    for (int kt = 0; kt < 4; ++kt) {
      s16x8 q = *reinterpret_cast<const s16x8*>(qp + kt * 32);
#pragma unroll
      for (int j = 0; j < 8; ++j) q[j] = bf16s(s2f(q[j]) * scaling);
      qf[kt] = q;
    }
  }
  s16x8 ones;
#pragma unroll
  for (int j = 0; j < 8; ++j) ones[j] = (short)0x3F80;  // bf16 1.0
  float mr[4], lr[4];
#pragma unroll
  for (int r = 0; r < 4; ++r) {
    mr[r] = -3.0e38f;
    lr[r] = 0.f;
  }
  f32x4 o[8] = {};
  const int cnt = sel_cnt[h];
  const int qmax = q0 + 63;
  for (int j0 = 0; j0 < cnt; j0 += BKV) {
    if (sel_idx[h * S_LEN + j0] > qmax) break;  // ascending list: rest is masked
    const int nk = min(BKV, cnt - j0);
    __syncthreads();
    if (tid < BKV) tIdx[tid] = (tid < nk) ? sel_idx[h * S_LEN + j0 + tid] : 0x7fffffff;
#pragma unroll
    for (int c = 0; c < 4; ++c) {
      const int ch = tid + c * 256;
      const int row = ch >> 4, c8 = ch & 15;
      if (row < nk) {
        const int t = sel_idx[h * S_LEN + j0 + row];
        *reinterpret_cast<s16x8*>(&Ks[row][c8 * 8]) = *reinterpret_cast<const s16x8*>(
            Kro + (size_t)t * (NKV * DH) + kv * DH + c8 * 8);
      }
    }
    {
      const int j = tid >> 2;                       // key slot 0..63
      const int dp = (tid & 3) * 32;                // dim chunk base
      const int ccA = j ^ (((dp >> 4) & 7) << 3);
      const int ccB = j ^ ((((dp >> 4) + 1) & 7) << 3);
      if (j < nk) {
        const int t = sel_idx[h * S_LEN + j0 + j];
        const __hip_bfloat16* vp = Vpk + (size_t)t * NQKV + kv * DH + dp;
        s16x8 a = *reinterpret_cast<const s16x8*>(vp);
        s16x8 bq = *reinterpret_cast<const s16x8*>(vp + 8);
        s16x8 cq = *reinterpret_cast<const s16x8*>(vp + 16);
        s16x8 dq = *reinterpret_cast<const s16x8*>(vp + 24);
#pragma unroll
        for (int i = 0; i < 8; ++i) reinterpret_cast<short&>(Vt[dp + i][ccA]) = a[i];
#pragma unroll
        for (int i = 0; i < 8; ++i) reinterpret_cast<short&>(Vt[dp + 8 + i][ccA]) = bq[i];
#pragma unroll
        for (int i = 0; i < 8; ++i) reinterpret_cast<short&>(Vt[dp + 16 + i][ccB]) = cq[i];
#pragma unroll
        for (int i = 0; i < 8; ++i) reinterpret_cast<short&>(Vt[dp + 24 + i][ccB]) = dq[i];
      } else {
#pragma unroll
        for (int i = 0; i < 16; ++i) reinterpret_cast<short&>(Vt[dp + i][ccA]) = 0;
#pragma unroll
        for (int i = 0; i < 16; ++i) reinterpret_cast<short&>(Vt[dp + 16 + i][ccB]) = 0;
      }
    }
    __syncthreads();
    // QK^T : D[q][key], four 16-key column tiles
    f32x4 sc[4];
#pragma unroll
    for (int kc = 0; kc < 4; ++kc) sc[kc] = f32x4{0.f, 0.f, 0.f, 0.f};
#pragma unroll
    for (int kt = 0; kt < 4; ++kt) {
#pragma unroll
      for (int kc = 0; kc < 4; ++kc) {
        const s16x8 kf =
            *reinterpret_cast<const s16x8*>(&Ks[kc * 16 + l15][kt * 32 + hi * 8]);
        sc[kc] = __builtin_amdgcn_mfma_f32_16x16x32_bf16(qf[kt], kf, sc[kc], 0, 0, 0);
      }
    }
    int tt[4];
#pragma unroll
    for (int kc = 0; kc < 4; ++kc) tt[kc] = tIdx[kc * 16 + l15];
    float vv[4][4];
    bool need = false;
#pragma unroll
    for (int r = 0; r < 4; ++r) {
      const int qs = qbase + (hi << 2) + r;
      float mx = -3.0e38f;
#pragma unroll
      for (int kc = 0; kc < 4; ++kc) {
        vv[kc][r] = (tt[kc] <= qs) ? sc[kc][r] : -1.0e9f;
        mx = fmaxf(mx, vv[kc][r]);
      }
      need = need || (mx > mr[r] + 8.f);
    }
    if (__any(need)) {  // rare path: true row-max via shfl, then rescale
#pragma unroll
      for (int r = 0; r < 4; ++r) {
        float m = fmaxf(fmaxf(vv[0][r], vv[1][r]), fmaxf(vv[2][r], vv[3][r]));
#pragma unroll
        for (int off = 1; off < 16; off <<= 1) m = fmaxf(m, __shfl_xor(m, off));
        const float mn = fmaxf(mr[r], m);
        const float scl = __expf(mr[r] - mn);
        lr[r] *= scl;
#pragma unroll
        for (int nt = 0; nt < 8; ++nt) o[nt][r] *= scl;
        mr[r] = mn;
      }
    }
#pragma unroll
    for (int r = 0; r < 4; ++r) {
#pragma unroll
      for (int kc = 0; kc < 4; ++kc) {
        Ps[wid][(hi << 2) + r][kc * 16 + l15] = __float2bfloat16(__expf(vv[kc][r] - mr[r]));
      }
    }
    const s16x8 pf0 = *reinterpret_cast<const s16x8*>(&Ps[wid][l15][hi * 8]);
    const s16x8 pf1 = *reinterpret_cast<const s16x8*>(&Ps[wid][l15][32 + hi * 8]);
    {  // row-sum via ones-broadcast MFMA
      f32x4 zero = {0.f, 0.f, 0.f, 0.f};
      f32x4 ps = __builtin_amdgcn_mfma_f32_16x16x32_bf16(pf0, ones, zero, 0, 0, 0);
      ps = __builtin_amdgcn_mfma_f32_16x16x32_bf16(pf1, ones, ps, 0, 0, 0);
#pragma unroll
      for (int r = 0; r < 4; ++r) lr[r] += ps[r];
    }
#pragma unroll
    for (int nt = 0; nt < 8; ++nt) {
      const s16x8 vfa =
          *reinterpret_cast<const s16x8*>(&Vt[nt * 16 + l15][(hi * 8) ^ (nt * 8)]);
      const s16x8 vfb =
          *reinterpret_cast<const s16x8*>(&Vt[nt * 16 + l15][(32 + hi * 8) ^ (nt * 8)]);
      o[nt] = __builtin_amdgcn_mfma_f32_16x16x32_bf16(pf0, vfa, o[nt], 0, 0, 0);
      o[nt] = __builtin_amdgcn_mfma_f32_16x16x32_bf16(pf1, vfb, o[nt], 0, 0, 0);
    }
  }
#pragma unroll
  for (int nt = 0; nt < 8; ++nt)
#pragma unroll
    for (int r = 0; r < 4; ++r) {
      const int qs = qbase + (hi << 2) + r;
      const int d = nt * 16 + l15;
      ctx[(size_t)qs * (NH * DH) + h * DH + d] = __float2bfloat16(o[nt][r] / lr[r]);
    }
}

}  // namespace

extern "C" void kernel_launch(void* const* d_in, const int* in_sizes, int n_in,
                              void* d_out, int out_size, void* d_ws, size_t ws_size,
                              hipStream_t stream) {
  const float* hidden = (const float*)d_in[0];
  const float* cosb = (const float*)d_in[1];
  const float* sinb = (const float*)d_in[2];
  const float* q_probs = (const float*)d_in[3];
  const float* v_norm = (const float*)d_in[4];
  const int* allowed = (const int*)d_in[5];
  const int* k_hard = (const int*)d_in[6];
  const float* Wq = (const float*)d_in[7];
  const float* Wk = (const float*)d_in[8];
  const float* Wv = (const float*)d_in[9];
  const float* Wo = (const float*)d_in[10];
  const int* sinkp = (const int*)d_in[11];
  const int* winp = (const int*)d_in[12];
  const int* Mp = (const int*)d_in[13];

  char* ws = (char*)d_ws;
  size_t off = 0;
  auto alloc = [&](size_t bytes) -> char* {
    char* p = ws + off;
    off += (bytes + 255) & ~(size_t)255;
    return p;
  };
  __hip_bfloat16* hbf = (__hip_bfloat16*)alloc((size_t)S_LEN * DM * 2);
  __hip_bfloat16* WqkvT = (__hip_bfloat16*)alloc((size_t)NQKV * DM * 2);  // packed [6144][4096]
  __hip_bfloat16* WoT = (__hip_bfloat16*)alloc((size_t)DM * DM * 2);
  __hip_bfloat16* QKV = (__hip_bfloat16*)alloc((size_t)S_LEN * NQKV * 2);
  __hip_bfloat16* Qro = (__hip_bfloat16*)alloc((size_t)S_LEN * NH * DH * 2);
  __hip_bfloat16* Kro = (__hip_bfloat16*)alloc((size_t)S_LEN * NKV * DH * 2);
  __hip_bfloat16* ctx = (__hip_bfloat16*)alloc((size_t)S_LEN * NH * DH * 2);
  int* sel_idx = (int*)alloc((size_t)NH * S_LEN * 4);
  int* sel_cnt = (int*)alloc((size_t)NH * 4);
  if (off > ws_size) return;

  prep_kernel<<<12288, 256, 0, stream>>>(hidden, Wq, Wk, Wv, Wo, hbf, WqkvT, WoT);

  gemm_bt<false><<<dim3(NQKV / 128, S_LEN / 128), 256, 0, stream>>>(
      hbf, WqkvT, (void*)QKV, NQKV, DM);

  rope_kernel<<<S_LEN, 256, 0, stream>>>(QKV, cosb, sinb, Qro, Kro);

  select_kernel<<<NH, 1024, 0, stream>>>(q_probs, v_norm, allowed, k_hard, sinkp, winp, Mp,
                                         sel_idx, sel_cnt);

  attn_kernel<<<dim3(S_LEN / 64, NH), 256, 0, stream>>>(Qro, Kro, QKV + VOFF, sel_idx,
                                                        sel_cnt, ctx);

  gemm_bt<true><<<dim3(DM / 128, S_LEN / 128), 256, 0, stream>>>(ctx, WoT, d_out, DM, DM);
}

// Round 8
// 385.637 us; speedup vs baseline: 3.2046x; 1.0054x over previous
//
#include <hip/hip_runtime.h>
#include <hip/hip_bf16.h>
#include <cstdint>
#include <cstddef>

namespace {

constexpr int S_LEN = 2048;
constexpr int DM    = 4096;
constexpr int NH    = 32;
constexpr int NKV   = 8;
constexpr int DH    = 128;
constexpr int LTAB  = 20;
constexpr int RBKT  = 128;
constexpr int NQKV  = NH * DH + 2 * NKV * DH;  // 6144 packed Q|K|V cols
constexpr int KOFF  = NH * DH;                 // 4096
constexpr int VOFF  = NH * DH + NKV * DH;      // 5120

typedef short s16x8 __attribute__((ext_vector_type(8)));
typedef float f32x4 __attribute__((ext_vector_type(4)));
typedef unsigned long long u64;
struct u64x2 { u64 x, y; };

__device__ inline short bf16s(float f) {
  __hip_bfloat16 b = __float2bfloat16(f);
  return (short)*reinterpret_cast<unsigned short*>(&b);
}
__device__ inline float s2f(short s) {
  unsigned short u = (unsigned short)s;
  return __bfloat162float(*reinterpret_cast<__hip_bfloat16*>(&u));
}

// ------- fused prep: select(32) + cvt(hidden->bf16) + 4 weight transposes, 1 dispatch -------
// regions: [0,32) select; [32,2080) cvt; [2080,6176) Wq; [6176,7200) Wk;
//          [7200,8224) Wv; [8224,12320) Wo
__global__ __launch_bounds__(256) void prep_kernel(
    const float* __restrict__ hidden, const float* __restrict__ Wq,
    const float* __restrict__ Wk, const float* __restrict__ Wv,
    const float* __restrict__ Wo, __hip_bfloat16* __restrict__ hbf,
    __hip_bfloat16* __restrict__ WqkvT, __hip_bfloat16* __restrict__ WoT,
    const float* __restrict__ q_probs, const float* __restrict__ v_norm,
    const int* __restrict__ allowed, const int* __restrict__ k_hard,
    const int* __restrict__ sinkp, const int* __restrict__ winp,
    const int* __restrict__ Mp, int* __restrict__ sel_idx, int* __restrict__ sel_cnt) {
  __shared__ float tile[64][65];
  __shared__ u64 keys[S_LEN];
  __shared__ int waveTot[4];
  const int b = blockIdx.x, tid = threadIdx.x;
  if (b < 32) {  // ---- top-M selection, 256 threads x 8 candidates ----
    const int h = b;
    const int lane = tid & 63, wv4 = tid >> 6;
    const int t0 = tid * 8;
    float cs[8] = {0.f, 0.f, 0.f, 0.f, 0.f, 0.f, 0.f, 0.f};
#pragma unroll
    for (int l = 0; l < LTAB; ++l) {
      const int* kb = &k_hard[(size_t)(h * LTAB + l) * S_LEN + t0];
      const int4 ka = *reinterpret_cast<const int4*>(kb);
      const int4 kc = *reinterpret_cast<const int4*>(kb + 4);
      const float* qp = &q_probs[(h * LTAB + l) * RBKT];
      cs[0] += qp[ka.x]; cs[1] += qp[ka.y]; cs[2] += qp[ka.z]; cs[3] += qp[ka.w];
      cs[4] += qp[kc.x]; cs[5] += qp[kc.y]; cs[6] += qp[kc.z]; cs[7] += qp[kc.w];
    }
    const int4 alA = *reinterpret_cast<const int4*>(&allowed[h * S_LEN + t0]);
    const int4 alB = *reinterpret_cast<const int4*>(&allowed[h * S_LEN + t0 + 4]);
    const float4 vnA = *reinterpret_cast<const float4*>(&v_norm[h * S_LEN + t0]);
    const float4 vnB = *reinterpret_cast<const float4*>(&v_norm[h * S_LEN + t0 + 4]);
    const int al[8] = {alA.x, alA.y, alA.z, alA.w, alB.x, alB.y, alB.z, alB.w};
    const float vn[8] = {vnA.x, vnA.y, vnA.z, vnA.w, vnB.x, vnB.y, vnB.z, vnB.w};
    auto mkkey = [](float s, int t) -> u64 {
      unsigned m = __float_as_uint(s);
      m = (m & 0x80000000u) ? ~m : (m | 0x80000000u);
      return ((u64)m << 11) | (u64)(S_LEN - 1 - t);
    };
    u64 kk[8];
#pragma unroll
    for (int c = 0; c < 8; ++c) {
      const float sc = al[c] ? cs[c] * vn[c] : -INFINITY;
      kk[c] = mkkey(sc, t0 + c);
      keys[t0 + c] = kk[c];
    }
    __syncthreads();
    int rk[8] = {0, 0, 0, 0, 0, 0, 0, 0};
#pragma unroll 4
    for (int u = 0; u < S_LEN; u += 2) {
      const u64x2 kv = *reinterpret_cast<const u64x2*>(&keys[u]);
#pragma unroll
      for (int c = 0; c < 8; ++c) rk[c] += (kv.x > kk[c]) + (kv.y > kk[c]);
    }
    const int Mv = min(Mp[0], S_LEN);
    int sv = sinkp[0];
    sv = sv < 0 ? 0 : (sv > S_LEN ? S_LEN : sv);
    int wvv = winp[0];
    wvv = wvv < 0 ? 0 : (wvv > S_LEN ? S_LEN : wvv);
    int wstart = S_LEN - wvv;
    if (wstart < sv) wstart = sv;
    bool sel[8];
    int cnt = 0;
#pragma unroll
    for (int c = 0; c < 8; ++c) {
      const int t = t0 + c;
      bool s = rk[c] < Mv;
      if (t < sv) s = true;
      if (wvv > 0 && t >= wstart) s = true;
      if (sv == 0 && wvv == 0 && t == S_LEN - 1) s = true;
      s = s && (al[c] != 0);
      sel[c] = s;
      cnt += s ? 1 : 0;
    }
    int inc = cnt;
#pragma unroll
    for (int off = 1; off < 64; off <<= 1) {
      int n = __shfl_up(inc, off);
      if (lane >= off) inc += n;
    }
    if (lane == 63) waveTot[wv4] = inc;
    __syncthreads();
    int wbase = 0;
    for (int w = 0; w < wv4; ++w) wbase += waveTot[w];
    int pos = wbase + inc - cnt;
    if (tid == 0) sel_cnt[h] = waveTot[0] + waveTot[1] + waveTot[2] + waveTot[3];
#pragma unroll
    for (int c = 0; c < 8; ++c)
      if (sel[c]) sel_idx[h * S_LEN + pos++] = t0 + c;
    return;
  }
  if (b < 32 + 2048) {  // ---- cvt: 1024 float4 per block ----
    const size_t base = (size_t)(b - 32) * 1024;
#pragma unroll
    for (int it = 0; it < 4; ++it) {
      const size_t i = base + it * 256 + tid;
      float4 v = reinterpret_cast<const float4*>(hidden)[i];
      ushort4 o;
      o.x = (unsigned short)bf16s(v.x);
      o.y = (unsigned short)bf16s(v.y);
      o.z = (unsigned short)bf16s(v.z);
      o.w = (unsigned short)bf16s(v.w);
      reinterpret_cast<ushort4*>(hbf)[i] = o;
    }
    return;
  }
  const float* W;
  __hip_bfloat16* Wt;
  int N, bx, by;
  int t = b - 2080;
  if (t < 4096) {
    W = Wq; Wt = WqkvT; N = DM; bx = t & 63; by = t >> 6;
  } else if (t < 5120) {
    t -= 4096; W = Wk; Wt = WqkvT + (size_t)KOFF * DM; N = NKV * DH; bx = t & 15; by = t >> 4;
  } else if (t < 6144) {
    t -= 5120; W = Wv; Wt = WqkvT + (size_t)VOFF * DM; N = NKV * DH; bx = t & 15; by = t >> 4;
  } else {
    t -= 6144; W = Wo; Wt = WoT; N = DM; bx = t & 63; by = t >> 6;
  }
  const int K = DM;
  const int kb = by * 64, nb = bx * 64;
  const int r0 = tid >> 4, c4 = (tid & 15) * 4;
#pragma unroll
  for (int it = 0; it < 4; ++it) {
    const int r = r0 + it * 16;
    float4 v = *reinterpret_cast<const float4*>(&W[(size_t)(kb + r) * N + nb + c4]);
    tile[r][c4] = v.x;
    tile[r][c4 + 1] = v.y;
    tile[r][c4 + 2] = v.z;
    tile[r][c4 + 3] = v.w;
  }
  __syncthreads();
  const int n0 = tid >> 4, k4 = (tid & 15) * 4;
#pragma unroll
  for (int it = 0; it < 4; ++it) {
    const int n = n0 + it * 16;
    ushort4 o;
    o.x = (unsigned short)bf16s(tile[k4][n]);
    o.y = (unsigned short)bf16s(tile[k4 + 1][n]);
    o.z = (unsigned short)bf16s(tile[k4 + 2][n]);
    o.w = (unsigned short)bf16s(tile[k4 + 3][n]);
    *reinterpret_cast<ushort4*>(&Wt[(size_t)(nb + n) * K + kb + k4]) = o;
  }
}

// ---------------- bf16 GEMM: C[M][N] = A[M][K] * Bt[N][K]^T ----------------
// 128x128 tile, BK=64, 4 waves (2x2), mfma 16x16x32, swizzled global_load_lds staging.
template <bool OUT_F32>
__global__ __launch_bounds__(256) void gemm_bt(const __hip_bfloat16* __restrict__ A,
                                               const __hip_bfloat16* __restrict__ Bt,
                                               void* __restrict__ Cout,
                                               int N, int K) {
  __shared__ __hip_bfloat16 As[128 * 64];
  __shared__ __hip_bfloat16 Bs[128 * 64];
  const int tid = threadIdx.x;
  const int wid = tid >> 6;
  const int lane = tid & 63;
  const int bm = blockIdx.y, bn = blockIdx.x;
  const int wr = wid >> 1, wc = wid & 1;
  f32x4 acc[4][4] = {};
  const __hip_bfloat16* Abase = A + (size_t)bm * 128 * K;
  const __hip_bfloat16* Bbase = Bt + (size_t)bn * 128 * K;
  for (int kt = 0; kt < K; kt += 64) {
    __syncthreads();
#pragma unroll
    for (int j = 0; j < 4; ++j) {
      const int pb = j * 4096 + wid * 1024;
      const int p = pb + lane * 16;
      const int row = p >> 7;
      const int slot = ((p >> 4) & 7) ^ (row & 7);
      const int goff = row * K + kt + slot * 8;
      __builtin_amdgcn_global_load_lds(
          (const __attribute__((address_space(1))) void*)(Abase + goff),
          (__attribute__((address_space(3))) void*)(As + (pb >> 1)), 16, 0, 0);
      __builtin_amdgcn_global_load_lds(
          (const __attribute__((address_space(1))) void*)(Bbase + goff),
          (__attribute__((address_space(3))) void*)(Bs + (pb >> 1)), 16, 0, 0);
    }
    __syncthreads();
#pragma unroll
    for (int kk = 0; kk < 2; ++kk) {
      s16x8 af[4], bf[4];
#pragma unroll
      for (int i = 0; i < 4; ++i) {
        const int ra = wr * 64 + i * 16 + (lane & 15);
        const int sa = (kk * 4 + (lane >> 4)) ^ (ra & 7);
        af[i] = *reinterpret_cast<const s16x8*>(As + ra * 64 + sa * 8);
        const int rb = wc * 64 + i * 16 + (lane & 15);
        const int sb = (kk * 4 + (lane >> 4)) ^ (rb & 7);
        bf[i] = *reinterpret_cast<const s16x8*>(Bs + rb * 64 + sb * 8);
      }
#pragma unroll
      for (int i = 0; i < 4; ++i)
#pragma unroll
        for (int jn = 0; jn < 4; ++jn)
          acc[i][jn] = __builtin_amdgcn_mfma_f32_16x16x32_bf16(af[i], bf[jn], acc[i][jn], 0, 0, 0);
    }
  }
  const int rg = (lane >> 4) * 4;
  const int cg = lane & 15;
#pragma unroll
  for (int i = 0; i < 4; ++i)
#pragma unroll
    for (int jn = 0; jn < 4; ++jn)
#pragma unroll
      for (int r = 0; r < 4; ++r) {
        const int rr = bm * 128 + wr * 64 + i * 16 + rg + r;
        const int cc = bn * 128 + wc * 64 + jn * 16 + cg;
        if (OUT_F32)
          reinterpret_cast<float*>(Cout)[(size_t)rr * N + cc] = acc[i][jn][r];
        else
          reinterpret_cast<__hip_bfloat16*>(Cout)[(size_t)rr * N + cc] =
              __float2bfloat16(acc[i][jn][r]);
      }
}

// ---- split-K variant: z-th K-half into P + z*M*N (f32). 2x blocks -> 4 blocks/CU ----
__global__ __launch_bounds__(256) void gemm_bt_splitk(const __hip_bfloat16* __restrict__ A,
                                                      const __hip_bfloat16* __restrict__ Bt,
                                                      float* __restrict__ P,
                                                      int N, int Kfull, int KH) {
  __shared__ __hip_bfloat16 As[128 * 64];
  __shared__ __hip_bfloat16 Bs[128 * 64];
  const int tid = threadIdx.x;
  const int wid = tid >> 6;
  const int lane = tid & 63;
  const int bm = blockIdx.y, bn = blockIdx.x, kz = blockIdx.z;
  const int wr = wid >> 1, wc = wid & 1;
  f32x4 acc[4][4] = {};
  const __hip_bfloat16* Abase = A + (size_t)bm * 128 * Kfull + kz * KH;
  const __hip_bfloat16* Bbase = Bt + (size_t)bn * 128 * Kfull + kz * KH;
  for (int kt = 0; kt < KH; kt += 64) {
    __syncthreads();
#pragma unroll
    for (int j = 0; j < 4; ++j) {
      const int pb = j * 4096 + wid * 1024;
      const int p = pb + lane * 16;
      const int row = p >> 7;
      const int slot = ((p >> 4) & 7) ^ (row & 7);
      const int goff = row * Kfull + kt + slot * 8;
      __builtin_amdgcn_global_load_lds(
          (const __attribute__((address_space(1))) void*)(Abase + goff),
          (__attribute__((address_space(3))) void*)(As + (pb >> 1)), 16, 0, 0);
      __builtin_amdgcn_global_load_lds(
          (const __attribute__((address_space(1))) void*)(Bbase + goff),
          (__attribute__((address_space(3))) void*)(Bs + (pb >> 1)), 16, 0, 0);
    }
    __syncthreads();
#pragma unroll
    for (int kk = 0; kk < 2; ++kk) {
      s16x8 af[4], bf[4];
#pragma unroll
      for (int i = 0; i < 4; ++i) {
        const int ra = wr * 64 + i * 16 + (lane & 15);
        const int sa = (kk * 4 + (lane >> 4)) ^ (ra & 7);
        af[i] = *reinterpret_cast<const s16x8*>(As + ra * 64 + sa * 8);
        const int rb = wc * 64 + i * 16 + (lane & 15);
        const int sb = (kk * 4 + (lane >> 4)) ^ (rb & 7);
        bf[i] = *reinterpret_cast<const s16x8*>(Bs + rb * 64 + sb * 8);
      }
#pragma unroll
      for (int i = 0; i < 4; ++i)
#pragma unroll
        for (int jn = 0; jn < 4; ++jn)
          acc[i][jn] = __builtin_amdgcn_mfma_f32_16x16x32_bf16(af[i], bf[jn], acc[i][jn], 0, 0, 0);
    }
  }
  float* Pz = P + (size_t)kz * S_LEN * N;
  const int rg = (lane >> 4) * 4;
  const int cg = lane & 15;
#pragma unroll
  for (int i = 0; i < 4; ++i)
#pragma unroll
    for (int jn = 0; jn < 4; ++jn)
#pragma unroll
      for (int r = 0; r < 4; ++r) {
        const int rr = bm * 128 + wr * 64 + i * 16 + rg + r;
        const int cc = bn * 128 + wc * 64 + jn * 16 + cg;
        Pz[(size_t)rr * N + cc] = acc[i][jn][r];
      }
}

__global__ __launch_bounds__(256) void reduce_splitk(const float* __restrict__ P,
                                                     float* __restrict__ out, int n4) {
  const int i = blockIdx.x * 256 + threadIdx.x;
  if (i >= n4) return;
  const float4 a = reinterpret_cast<const float4*>(P)[i];
  const float4 b = reinterpret_cast<const float4*>(P + (size_t)S_LEN * DM)[i];
  float4 o;
  o.x = a.x + b.x;
  o.y = a.y + b.y;
  o.z = a.z + b.z;
  o.w = a.w + b.w;
  reinterpret_cast<float4*>(out)[i] = o;
}

// ---------------- RoPE on packed QKV -> Qro [S][4096], Kro [S][1024] ----------------
__global__ __launch_bounds__(256) void rope_kernel(const __hip_bfloat16* __restrict__ QKV,
                                                   const float* __restrict__ cosb,
                                                   const float* __restrict__ sinb,
                                                   __hip_bfloat16* __restrict__ Qro,
                                                   __hip_bfloat16* __restrict__ Kro) {
  const int s = blockIdx.x;
  const int tid = threadIdx.x;
  const float* cs = cosb + s * DH;
  const float* sn = sinb + s * DH;
  const __hip_bfloat16* row = QKV + (size_t)s * NQKV;
  for (int ch = tid; ch < 512 + 128; ch += 256) {
    const bool isQ = ch < 512;
    const int idx8 = (isQ ? ch : ch - 512) * 8;
    const int d8 = idx8 & (DH - 1);
    const int hb = idx8 - d8;
    const __hip_bfloat16* src = isQ ? row : row + KOFF;
    s16x8 v = *reinterpret_cast<const s16x8*>(src + idx8);
    s16x8 p = *reinterpret_cast<const s16x8*>(src + hb + (d8 ^ 64));
    const float sgn = (d8 < 64) ? -1.f : 1.f;
    s16x8 outv;
#pragma unroll
    for (int j = 0; j < 8; ++j) {
      const float r = s2f(v[j]) * cs[d8 + j] + sgn * s2f(p[j]) * sn[d8 + j];
      outv[j] = bf16s(r);
    }
    if (isQ)
      *reinterpret_cast<s16x8*>(Qro + (size_t)s * (NH * DH) + idx8) = outv;
    else
      *reinterpret_cast<s16x8*>(Kro + (size_t)s * (NKV * DH) + idx8) = outv;
  }
}

// ---------------- flash attention, BKV=64 ----------------
__global__ __launch_bounds__(256) void attn_kernel(const __hip_bfloat16* __restrict__ Qro,
                                                   const __hip_bfloat16* __restrict__ Kro,
                                                   const __hip_bfloat16* __restrict__ Vpk,
                                                   const int* __restrict__ sel_idx,
                                                   const int* __restrict__ sel_cnt,
                                                   __hip_bfloat16* __restrict__ ctx) {
  constexpr int BKV = 64;
  const int h = blockIdx.y;
  const int q0 = blockIdx.x * 64;
  const int tid = threadIdx.x, wid = tid >> 6, lane = tid & 63;
  const int l15 = lane & 15, hi = lane >> 4;
  const int kv = h >> 2;
  __shared__ __hip_bfloat16 Ks[BKV][DH + 8];
  __shared__ __hip_bfloat16 Vt[DH][BKV + 8];
  __shared__ __hip_bfloat16 Ps[4][16][BKV + 8];
  __shared__ int tIdx[BKV];
  const int qbase = q0 + wid * 16;
  const float scaling = 0.08838834764831845f;  // 128^-0.5 (pre-applied to Q)
  s16x8 qf[4];
  {
    const __hip_bfloat16* qp =
        Qro + (size_t)(qbase + l15) * (NH * DH) + h * DH + hi * 8;
#pragma unroll
    for (int kt = 0; kt < 4; ++kt) {
      s16x8 q = *reinterpret_cast<const s16x8*>(qp + kt * 32);
#pragma unroll
      for (int j = 0; j < 8; ++j) q[j] = bf16s(s2f(q[j]) * scaling);
      qf[kt] = q;
    }
  }
  s16x8 ones;
#pragma unroll
  for (int j = 0; j < 8; ++j) ones[j] = (short)0x3F80;  // bf16 1.0
  float mr[4], lr[4];
#pragma unroll
  for (int r = 0; r < 4; ++r) {
    mr[r] = -3.0e38f;
    lr[r] = 0.f;
  }
  f32x4 o[8] = {};
  const int cnt = sel_cnt[h];
  const int qmax = q0 + 63;
  for (int j0 = 0; j0 < cnt; j0 += BKV) {
    if (sel_idx[h * S_LEN + j0] > qmax) break;
    const int nk = min(BKV, cnt - j0);
    __syncthreads();
    if (tid < BKV) tIdx[tid] = (tid < nk) ? sel_idx[h * S_LEN + j0 + tid] : 0x7fffffff;
#pragma unroll
    for (int c = 0; c < 4; ++c) {
      const int ch = tid + c * 256;
      const int row = ch >> 4, c8 = ch & 15;
      if (row < nk) {
        const int t = sel_idx[h * S_LEN + j0 + row];
        *reinterpret_cast<s16x8*>(&Ks[row][c8 * 8]) = *reinterpret_cast<const s16x8*>(
            Kro + (size_t)t * (NKV * DH) + kv * DH + c8 * 8);
      }
    }
    {
      const int j = tid >> 2;
      const int dp = (tid & 3) * 32;
      const int ccA = j ^ (((dp >> 4) & 7) << 3);
      const int ccB = j ^ ((((dp >> 4) + 1) & 7) << 3);
      if (j < nk) {
        const int t = sel_idx[h * S_LEN + j0 + j];
        const __hip_bfloat16* vp = Vpk + (size_t)t * NQKV + kv * DH + dp;
        s16x8 a = *reinterpret_cast<const s16x8*>(vp);
        s16x8 bq = *reinterpret_cast<const s16x8*>(vp + 8);
        s16x8 cq = *reinterpret_cast<const s16x8*>(vp + 16);
        s16x8 dq = *reinterpret_cast<const s16x8*>(vp + 24);
#pragma unroll
        for (int i = 0; i < 8; ++i) reinterpret_cast<short&>(Vt[dp + i][ccA]) = a[i];
#pragma unroll
        for (int i = 0; i < 8; ++i) reinterpret_cast<short&>(Vt[dp + 8 + i][ccA]) = bq[i];
#pragma unroll
        for (int i = 0; i < 8; ++i) reinterpret_cast<short&>(Vt[dp + 16 + i][ccB]) = cq[i];
#pragma unroll
        for (int i = 0; i < 8; ++i) reinterpret_cast<short&>(Vt[dp + 24 + i][ccB]) = dq[i];
      } else {
#pragma unroll
        for (int i = 0; i < 16; ++i) reinterpret_cast<short&>(Vt[dp + i][ccA]) = 0;
#pragma unroll
        for (int i = 0; i < 16; ++i) reinterpret_cast<short&>(Vt[dp + 16 + i][ccB]) = 0;
      }
    }
    __syncthreads();
    f32x4 sc[4];
#pragma unroll
    for (int kc = 0; kc < 4; ++kc) sc[kc] = f32x4{0.f, 0.f, 0.f, 0.f};
#pragma unroll
    for (int kt = 0; kt < 4; ++kt) {
#pragma unroll
      for (int kc = 0; kc < 4; ++kc) {
        const s16x8 kf =
            *reinterpret_cast<const s16x8*>(&Ks[kc * 16 + l15][kt * 32 + hi * 8]);
        sc[kc] = __builtin_amdgcn_mfma_f32_16x16x32_bf16(qf[kt], kf, sc[kc], 0, 0, 0);
      }
    }
    int tt[4];
#pragma unroll
    for (int kc = 0; kc < 4; ++kc) tt[kc] = tIdx[kc * 16 + l15];
    float vv[4][4];
    bool need = false;
#pragma unroll
    for (int r = 0; r < 4; ++r) {
      const int qs = qbase + (hi << 2) + r;
      float mx = -3.0e38f;
#pragma unroll
      for (int kc = 0; kc < 4; ++kc) {
        vv[kc][r] = (tt[kc] <= qs) ? sc[kc][r] : -1.0e9f;
        mx = fmaxf(mx, vv[kc][r]);
      }
      need = need || (mx > mr[r] + 8.f);
    }
    if (__any(need)) {
#pragma unroll
      for (int r = 0; r < 4; ++r) {
        float m = fmaxf(fmaxf(vv[0][r], vv[1][r]), fmaxf(vv[2][r], vv[3][r]));
#pragma unroll
        for (int off = 1; off < 16; off <<= 1) m = fmaxf(m, __shfl_xor(m, off));
        const float mn = fmaxf(mr[r], m);
        const float scl = __expf(mr[r] - mn);
        lr[r] *= scl;
#pragma unroll
        for (int nt = 0; nt < 8; ++nt) o[nt][r] *= scl;
        mr[r] = mn;
      }
    }
#pragma unroll
    for (int r = 0; r < 4; ++r) {
#pragma unroll
      for (int kc = 0; kc < 4; ++kc) {
        Ps[wid][(hi << 2) + r][kc * 16 + l15] = __float2bfloat16(__expf(vv[kc][r] - mr[r]));
      }
    }
    const s16x8 pf0 = *reinterpret_cast<const s16x8*>(&Ps[wid][l15][hi * 8]);
    const s16x8 pf1 = *reinterpret_cast<const s16x8*>(&Ps[wid][l15][32 + hi * 8]);
    {
      f32x4 zero = {0.f, 0.f, 0.f, 0.f};
      f32x4 ps = __builtin_amdgcn_mfma_f32_16x16x32_bf16(pf0, ones, zero, 0, 0, 0);
      ps = __builtin_amdgcn_mfma_f32_16x16x32_bf16(pf1, ones, ps, 0, 0, 0);
#pragma unroll
      for (int r = 0; r < 4; ++r) lr[r] += ps[r];
    }
#pragma unroll
    for (int nt = 0; nt < 8; ++nt) {
      const s16x8 vfa =
          *reinterpret_cast<const s16x8*>(&Vt[nt * 16 + l15][(hi * 8) ^ (nt * 8)]);
      const s16x8 vfb =
          *reinterpret_cast<const s16x8*>(&Vt[nt * 16 + l15][(32 + hi * 8) ^ (nt * 8)]);
      o[nt] = __builtin_amdgcn_mfma_f32_16x16x32_bf16(pf0, vfa, o[nt], 0, 0, 0);
      o[nt] = __builtin_amdgcn_mfma_f32_16x16x32_bf16(pf1, vfb, o[nt], 0, 0, 0);
    }
  }
#pragma unroll
  for (int nt = 0; nt < 8; ++nt)
#pragma unroll
    for (int r = 0; r < 4; ++r) {
      const int qs = qbase + (hi << 2) + r;
      const int d = nt * 16 + l15;
      ctx[(size_t)qs * (NH * DH) + h * DH + d] = __float2bfloat16(o[nt][r] / lr[r]);
    }
}

}  // namespace

extern "C" void kernel_launch(void* const* d_in, const int* in_sizes, int n_in,
                              void* d_out, int out_size, void* d_ws, size_t ws_size,
                              hipStream_t stream) {
  const float* hidden = (const float*)d_in[0];
  const float* cosb = (const float*)d_in[1];
  const float* sinb = (const float*)d_in[2];
  const float* q_probs = (const float*)d_in[3];
  const float* v_norm = (const float*)d_in[4];
  const int* allowed = (const int*)d_in[5];
  const int* k_hard = (const int*)d_in[6];
  const float* Wq = (const float*)d_in[7];
  const float* Wk = (const float*)d_in[8];
  const float* Wv = (const float*)d_in[9];
  const float* Wo = (const float*)d_in[10];
  const int* sinkp = (const int*)d_in[11];
  const int* winp = (const int*)d_in[12];
  const int* Mp = (const int*)d_in[13];

  char* ws = (char*)d_ws;
  size_t off = 0;
  auto alloc = [&](size_t bytes) -> char* {
    char* p = ws + off;
    off += (bytes + 255) & ~(size_t)255;
    return p;
  };
  __hip_bfloat16* hbf = (__hip_bfloat16*)alloc((size_t)S_LEN * DM * 2);
  __hip_bfloat16* WqkvT = (__hip_bfloat16*)alloc((size_t)NQKV * DM * 2);  // packed [6144][4096]
  __hip_bfloat16* WoT = (__hip_bfloat16*)alloc((size_t)DM * DM * 2);
  __hip_bfloat16* QKV = (__hip_bfloat16*)alloc((size_t)S_LEN * NQKV * 2);
  __hip_bfloat16* Qro = (__hip_bfloat16*)alloc((size_t)S_LEN * NH * DH * 2);
  __hip_bfloat16* Kro = (__hip_bfloat16*)alloc((size_t)S_LEN * NKV * DH * 2);
  __hip_bfloat16* ctx = (__hip_bfloat16*)alloc((size_t)S_LEN * NH * DH * 2);
  int* sel_idx = (int*)alloc((size_t)NH * S_LEN * 4);
  int* sel_cnt = (int*)alloc((size_t)NH * 4);
  if (off > ws_size) return;
  // split-K partials (2 x 33.5 MB f32) exactly overlay hbf+WqkvT (67.1 MB),
  // both dead once the QKV GEMM has completed (stream-serial).
  float* Psplit = (float*)hbf;

  prep_kernel<<<12320, 256, 0, stream>>>(hidden, Wq, Wk, Wv, Wo, hbf, WqkvT, WoT, q_probs,
                                         v_norm, allowed, k_hard, sinkp, winp, Mp, sel_idx,
                                         sel_cnt);

  gemm_bt<false><<<dim3(NQKV / 128, S_LEN / 128), 256, 0, stream>>>(
      hbf, WqkvT, (void*)QKV, NQKV, DM);

  rope_kernel<<<S_LEN, 256, 0, stream>>>(QKV, cosb, sinb, Qro, Kro);

  attn_kernel<<<dim3(S_LEN / 64, NH), 256, 0, stream>>>(Qro, Kro, QKV + VOFF, sel_idx,
                                                        sel_cnt, ctx);

  gemm_bt_splitk<<<dim3(DM / 128, S_LEN / 128, 2), 256, 0, stream>>>(ctx, WoT, Psplit, DM,
                                                                     DM, DM / 2);
  reduce_splitk<<<(S_LEN * DM / 4 + 255) / 256, 256, 0, stream>>>((const float*)Psplit,
                                                                  (float*)d_out,
                                                                  S_LEN * DM / 4);
}